// Round 9
// baseline (548.948 us; speedup 1.0000x reference)
//
#include <hip/hip_runtime.h>

#define S_LEN 2048
#define NHEAD 16
#define DHEAD 64
#define DMODEL 1024
#define BATCH 4
#define SC2 0.18033688011112042f   // 0.125 * log2(e)

typedef short bf16x8 __attribute__((ext_vector_type(8)));
typedef float f32x4 __attribute__((ext_vector_type(4)));
typedef unsigned short u16;
typedef unsigned short u16x8 __attribute__((ext_vector_type(8)));
typedef unsigned short u16x4 __attribute__((ext_vector_type(4)));
typedef unsigned long long u64;
typedef unsigned long long u64x2 __attribute__((ext_vector_type(2)));

__device__ __forceinline__ u16 f2b(float f) {
  unsigned u = __builtin_bit_cast(unsigned, f);
  u += 0x7FFFu + ((u >> 16) & 1u);   // RTNE
  return (u16)(u >> 16);
}
__device__ __forceinline__ float b2f(u16 v) {
  unsigned u = ((unsigned)v) << 16;
  return __builtin_bit_cast(float, u);
}
__device__ __forceinline__ f32x4 mfma16(bf16x8 a, bf16x8 b, f32x4 c) {
  return __builtin_amdgcn_mfma_f32_16x16x32_bf16(a, b, c, 0, 0, 0);
}
__device__ __forceinline__ void load_lds16(const void* g, void* l) {
  __builtin_amdgcn_global_load_lds(
      (const __attribute__((address_space(1))) unsigned int*)g,
      (__attribute__((address_space(3))) unsigned int*)l, 16, 0, 0);
}
// Batched raw v_exp_f32 (= 2^x exactly). One trailing s_nop covers the
// TRANS result-read hazard for the last op; the first three are covered by
// the following independent exps.
__device__ __forceinline__ void fexp2x4(float& a, float& b, float& c, float& d) {
  asm("v_exp_f32 %0, %0\n\t"
      "v_exp_f32 %1, %1\n\t"
      "v_exp_f32 %2, %2\n\t"
      "v_exp_f32 %3, %3\n\t"
      "s_nop 1"
      : "+v"(a), "+v"(b), "+v"(c), "+v"(d));
}
__device__ __forceinline__ unsigned cvtpk(float lo, float hi) {
  unsigned r;
  asm("v_cvt_pk_bf16_f32 %0, %1, %2" : "=v"(r) : "v"(lo), "v"(hi));
  return r;
}

// ---------------- prepass kernels ----------------

__global__ void cvt_f32_bf16(const float* __restrict__ src, u16* __restrict__ dst, int n4) {
  int i = blockIdx.x * 256 + threadIdx.x;
  int stride = gridDim.x * 256;
  for (; i < n4; i += stride) {
    float4 v = ((const float4*)src)[i];
    u16x4 o = { f2b(v.x), f2b(v.y), f2b(v.z), f2b(v.w) };
    ((u16x4*)dst)[i] = o;
  }
}

// mask [2048 q][2048 k] int -> Mex[(q*32+T)*16 + g*4 + t] u64 halfword AND-mask
// halfword r covers k = T*64 + t*16 + g*4 + r : 0xFFFF keep, 0 drop.
__global__ void mask_expand(const int* __restrict__ M, u64* __restrict__ Mex) {
  int idx = blockIdx.x * 256 + threadIdx.x;     // 1M groups of 4 elements
  int q = idx >> 9, k = (idx & 511) * 4;
  int4 v = *(const int4*)(M + (size_t)q * S_LEN + k);
  int T = k >> 6, t = (k >> 4) & 3, g = (k >> 2) & 3;
  u64 m = 0;
  if (!v.x) m |= 0xFFFFull;
  if (!v.y) m |= 0xFFFF0000ull;
  if (!v.z) m |= 0xFFFF00000000ull;
  if (!v.w) m |= 0xFFFF000000000000ull;
  Mex[((size_t)q * 32 + T) * 16 + g * 4 + t] = m;
}

// W [16][1024][64] f32 -> WT [1024 c][1024 d] bf16, c = n*64+h, scaled
__global__ void repack_w(const float* __restrict__ W, u16* __restrict__ WT, float scale) {
  __shared__ u16 t[64][66];
  const int tid = threadIdx.x;
  const int n = blockIdx.y, d0 = blockIdx.x * 64;
  const float* src = W + (size_t)n * 65536;
  for (int p = 0; p < 4; ++p) {
    int idx = p * 256 + tid;
    int r = idx >> 4, cs = idx & 15;
    float4 v = *(const float4*)(src + (size_t)(d0 + r) * 64 + cs * 4);
    t[r][cs*4+0] = f2b(v.x*scale); t[r][cs*4+1] = f2b(v.y*scale);
    t[r][cs*4+2] = f2b(v.z*scale); t[r][cs*4+3] = f2b(v.w*scale);
  }
  __syncthreads();
  for (int p = 0; p < 2; ++p) {
    int idx = p * 256 + tid;
    int hl = idx >> 3, ds = idx & 7;
    u16x8 o;
    for (int e = 0; e < 8; ++e) o[e] = t[ds*8+e][hl];
    *(u16x8*)(WT + (size_t)(n*64 + hl) * 1024 + d0 + ds*8) = o;
  }
}

// W_O [1024 c][1024 d] f32 -> WoT hi/lo [1024 d][1024 c] bf16
__global__ void split_wo(const float* __restrict__ Wo, u16* __restrict__ Hi, u16* __restrict__ Lo) {
  __shared__ u16 th[64][66];
  __shared__ u16 tl[64][66];
  const int tid = threadIdx.x;
  const int d0 = blockIdx.x * 64, c0 = blockIdx.y * 64;
  for (int p = 0; p < 4; ++p) {
    int idx = p * 256 + tid;
    int r = idx >> 4, cs = idx & 15;
    float4 v = *(const float4*)(Wo + (size_t)(c0 + r) * 1024 + d0 + cs * 4);
    float f[4] = {v.x, v.y, v.z, v.w};
    for (int e = 0; e < 4; ++e) {
      u16 hb = f2b(f[e]);
      th[r][cs*4+e] = hb;
      tl[r][cs*4+e] = f2b(f[e] - b2f(hb));
    }
  }
  __syncthreads();
  for (int p = 0; p < 2; ++p) {
    int idx = p * 256 + tid;
    int dr = idx >> 3, cs = idx & 7;
    u16x8 oh, ol;
    for (int e = 0; e < 8; ++e) { oh[e] = th[cs*8+e][dr]; ol[e] = tl[cs*8+e][dr]; }
    *(u16x8*)(Hi + (size_t)(d0 + dr) * 1024 + c0 + cs*8) = oh;
    *(u16x8*)(Lo + (size_t)(d0 + dr) * 1024 + c0 + cs*8) = ol;
  }
}

// v [8192][1024] bf16 -> VT [(b*16+h)*64 + dh][2048 s] bf16
__global__ void transpose_v(const u16* __restrict__ V, u16* __restrict__ VT) {
  __shared__ u16 t[64][66];
  const int tid = threadIdx.x;
  const int s0 = blockIdx.x * 64;
  const int b = blockIdx.y >> 4, h = blockIdx.y & 15;
  for (int p = 0; p < 2; ++p) {
    int idx = p * 256 + tid;
    int r = idx >> 3, sg = idx & 7;
    u16x8 v = *(const u16x8*)(V + (size_t)(b*S_LEN + s0 + r) * 1024 + h*64 + sg*8);
    for (int e = 0; e < 8; ++e) t[r][sg*8+e] = v[e];
  }
  __syncthreads();
  for (int p = 0; p < 2; ++p) {
    int idx = p * 256 + tid;
    int dr = idx >> 3, ss = idx & 7;
    u16x8 o;
    for (int e = 0; e < 8; ++e) o[e] = t[ss*8+e][dr];
    *(u16x8*)(VT + ((size_t)(b*NHEAD + h) * 64 + dr) * 2048 + s0 + ss*8) = o;
  }
}

// ---------------- GEMM: C[M][1024] = A[M][1024] * Bt[1024][1024]^T + bias*bscale ----------------

template<int BF16OUT>
__global__ __launch_bounds__(256, 2)
void gemm_bt(const u16* __restrict__ A, const u16* __restrict__ Bt,
             const float* __restrict__ bias, float bscale, void* __restrict__ Cout)
{
  __shared__ __align__(16) char As[16384];
  __shared__ __align__(16) char Bs[16384];
  const int tid = threadIdx.x, wid = tid >> 6, lane = tid & 63;
  const int lq = lane & 15, g = lane >> 4;
  const size_t am0 = (size_t)blockIdx.y * 128;
  const size_t bn0 = (size_t)blockIdx.x * 128;
  const int wr = (wid >> 1) * 64, wc = (wid & 1) * 64;
  f32x4 z4 = {0.f, 0.f, 0.f, 0.f};
  f32x4 acc[4][4];
  for (int i = 0; i < 4; ++i) for (int j = 0; j < 4; ++j) acc[i][j] = z4;
  for (int k0 = 0; k0 < DMODEL; k0 += 64) {
#pragma unroll
    for (int c = 0; c < 4; ++c) {
      int idx = c*256 + tid, r = idx >> 3, s = idx & 7;
      load_lds16(A + (am0 + r)*DMODEL + k0 + ((s ^ (r & 7)) << 3), As + idx*16);
    }
#pragma unroll
    for (int c = 0; c < 4; ++c) {
      int idx = c*256 + tid, r = idx >> 3, s = idx & 7;
      load_lds16(Bt + (bn0 + r)*DMODEL + k0 + ((s ^ (r & 7)) << 3), Bs + idx*16);
    }
    __syncthreads();
#pragma unroll
    for (int ks = 0; ks < 2; ++ks) {
      bf16x8 af[4], bfr[4];
#pragma unroll
      for (int i = 0; i < 4; ++i) {
        int row = wr + i*16 + lq;
        af[i] = *(const bf16x8*)(As + row*128 + (((ks*4 + g) ^ (row & 7)) << 4));
      }
#pragma unroll
      for (int j = 0; j < 4; ++j) {
        int row = wc + j*16 + lq;
        bfr[j] = *(const bf16x8*)(Bs + row*128 + (((ks*4 + g) ^ (row & 7)) << 4));
      }
#pragma unroll
      for (int i = 0; i < 4; ++i)
#pragma unroll
        for (int j = 0; j < 4; ++j)
          acc[i][j] = mfma16(af[i], bfr[j], acc[i][j]);
    }
    __syncthreads();
  }
#pragma unroll
  for (int i = 0; i < 4; ++i)
#pragma unroll
    for (int j = 0; j < 4; ++j) {
      size_t row = am0 + wr + i*16 + g*4;
      int col = (int)bn0 + wc + j*16 + lq;
      float bv = bias[col] * bscale;
#pragma unroll
      for (int r = 0; r < 4; ++r) {
        float v = acc[i][j][r] + bv;
        if (BF16OUT) ((u16*)Cout)[(row + r)*DMODEL + col] = f2b(v);
        else         ((float*)Cout)[(row + r)*DMODEL + col] = v;
      }
    }
}

// ---------------- out = Z(f32, split hi/lo) @ WoT^T + b_O ----------------

__global__ __launch_bounds__(256, 2)
void gemm_out(const float* __restrict__ Z, const u16* __restrict__ Bh,
              const u16* __restrict__ Bl, const float* __restrict__ bias,
              float* __restrict__ Cout)
{
  __shared__ __align__(16) char Ah[16384];
  __shared__ __align__(16) char Al[16384];
  __shared__ __align__(16) char Bhs[16384];
  __shared__ __align__(16) char Bls[16384];
  const int tid = threadIdx.x, wid = tid >> 6, lane = tid & 63;
  const int lq = lane & 15, g = lane >> 4;
  const size_t am0 = (size_t)blockIdx.y * 128;
  const size_t bn0 = (size_t)blockIdx.x * 128;
  const int wr = (wid >> 1) * 64, wc = (wid & 1) * 64;
  f32x4 z4 = {0.f, 0.f, 0.f, 0.f};
  f32x4 acc[4][4];
  for (int i = 0; i < 4; ++i) for (int j = 0; j < 4; ++j) acc[i][j] = z4;
  for (int k0 = 0; k0 < DMODEL; k0 += 64) {
#pragma unroll
    for (int c = 0; c < 8; ++c) {
      int idx = c*256 + tid, r = idx >> 4, fs = idx & 15;
      float4 v = *(const float4*)(Z + (am0 + r)*DMODEL + k0 + fs*4);
      float f[4] = {v.x, v.y, v.z, v.w};
      u16x4 hv, lv;
      for (int e = 0; e < 4; ++e) {
        u16 hb = f2b(f[e]);
        hv[e] = hb;
        lv[e] = f2b(f[e] - b2f(hb));
      }
      int byo = r*128 + ((((fs >> 1) ^ (r & 7)) << 4) | ((fs & 1) << 3));
      *(u16x4*)(Ah + byo) = hv;
      *(u16x4*)(Al + byo) = lv;
    }
#pragma unroll
    for (int c = 0; c < 4; ++c) {
      int idx = c*256 + tid, r = idx >> 3, s = idx & 7;
      load_lds16(Bh + (bn0 + r)*DMODEL + k0 + ((s ^ (r & 7)) << 3), Bhs + idx*16);
    }
#pragma unroll
    for (int c = 0; c < 4; ++c) {
      int idx = c*256 + tid, r = idx >> 3, s = idx & 7;
      load_lds16(Bl + (bn0 + r)*DMODEL + k0 + ((s ^ (r & 7)) << 3), Bls + idx*16);
    }
    __syncthreads();
#pragma unroll
    for (int ks = 0; ks < 2; ++ks) {
      bf16x8 ah[4], al[4], bh4[4], bl4[4];
#pragma unroll
      for (int i = 0; i < 4; ++i) {
        int row = wr + i*16 + lq;
        int off = row*128 + (((ks*4 + g) ^ (row & 7)) << 4);
        ah[i] = *(const bf16x8*)(Ah + off);
        al[i] = *(const bf16x8*)(Al + off);
      }
#pragma unroll
      for (int j = 0; j < 4; ++j) {
        int row = wc + j*16 + lq;
        int off = row*128 + (((ks*4 + g) ^ (row & 7)) << 4);
        bh4[j] = *(const bf16x8*)(Bhs + off);
        bl4[j] = *(const bf16x8*)(Bls + off);
      }
#pragma unroll
      for (int i = 0; i < 4; ++i)
#pragma unroll
        for (int j = 0; j < 4; ++j) {
          acc[i][j] = mfma16(al[i], bh4[j], acc[i][j]);
          acc[i][j] = mfma16(ah[i], bl4[j], acc[i][j]);
          acc[i][j] = mfma16(ah[i], bh4[j], acc[i][j]);
        }
    }
    __syncthreads();
  }
#pragma unroll
  for (int i = 0; i < 4; ++i)
#pragma unroll
    for (int j = 0; j < 4; ++j) {
      size_t row = am0 + wr + i*16 + g*4;
      int col = (int)bn0 + wc + j*16 + lq;
      float bv = bias[col];
#pragma unroll
      for (int r = 0; r < 4; ++r)
        Cout[(row + r)*DMODEL + col] = acc[i][j][r] + bv;
    }
}

// ---------------- flash attention ----------------
// grid 1024 blocks (XCD-swizzled (qt,h,b)), 256 threads = 4 waves x 32 q-rows
// LDS 32KB single-buffered: K @0 8K | V @8K 8K | P @16K per-wave 4K
// T14 reg-staging carries tile it+1 in registers across compute of tile it;
// [compute][bar][ds_write regs][bar]. launch_bounds(256,4): VGPR cap 128
// (current use ~84, no spills) -> 4 blocks/CU all resident, occupancy ~50%.
__global__ __launch_bounds__(256, 4)
void attn(const u16* __restrict__ Q, const u16* __restrict__ K,
          const u16* __restrict__ VT, const u64* __restrict__ Mex,
          float* __restrict__ Zf)
{
  __shared__ __align__(16) char L[32768];
  const int tid = threadIdx.x, wid = tid >> 6, lane = tid & 63;
  const int lq = lane & 15, g = lane >> 4;
  // XCD swizzle: all 16 q-tile blocks of one (b,h) on one XCD (round-robin %8)
  const int Lb = blockIdx.x;
  const int xcd = Lb & 7, slot = Lb >> 3;
  const int qt = slot & 15, pl = slot >> 4;
  const int pair = xcd * 8 + pl;          // 0..63
  const int h = pair & 15, b = pair >> 4;
  const int q0 = qt * 128;
  const int qw = q0 + wid * 32;

  bf16x8 qf[2][2];
#pragma unroll
  for (int u = 0; u < 2; ++u) {
    const u16* qp = Q + (size_t)(b*S_LEN + qw + u*16 + lq) * DMODEL + h*DHEAD + g*8;
    qf[u][0] = *(const bf16x8*)qp;
    qf[u][1] = *(const bf16x8*)(qp + 32);
  }
  bf16x8 ones;
#pragma unroll
  for (int e = 0; e < 8; ++e) ones[e] = (short)0x3F80;

  const f32x4 z4 = {0.f, 0.f, 0.f, 0.f};
  f32x4 Oc[2][4];
#pragma unroll
  for (int u = 0; u < 2; ++u)
#pragma unroll
    for (int t = 0; t < 4; ++t) Oc[u][t] = z4;
  f32x4 lrow[2] = {z4, z4};

  const u16* kp = K + (size_t)(b*S_LEN)*DMODEL + h*DHEAD;
  const u16* vp = VT + (size_t)((b*NHEAD + h)*DHEAD)*S_LEN;
  const u64* mx0 = Mex + (size_t)(qw + lq) * 512 + g*4;        // u=0 row
  const u64* mx1 = Mex + (size_t)(qw + 16 + lq) * 512 + g*4;   // u=1 row
  char* myP = L + 16384 + wid*4096;

  // per-thread staging offsets (pre-swizzled global sources, linear LDS dests)
  size_t ko[2], vo[2];
  int sd[2];
#pragma unroll
  for (int c = 0; c < 2; ++c) {
    int idx = c*256 + tid, r = idx >> 3, s = idx & 7, so = (s ^ (r & 7)) << 3;
    ko[c] = (size_t)r * DMODEL + so;
    vo[c] = (size_t)r * S_LEN + so;
    sd[c] = idx * 16;
  }

  // ---- prologue: tile 0 ----
  bf16x8 kr0, kr1, vr0, vr1;
  kr0 = *(const bf16x8*)(kp + ko[0]); kr1 = *(const bf16x8*)(kp + ko[1]);
  vr0 = *(const bf16x8*)(vp + vo[0]); vr1 = *(const bf16x8*)(vp + vo[1]);
  u64x2 m0a = *(const u64x2*)(mx0), m0b = *(const u64x2*)(mx0 + 2);
  u64x2 m1a = *(const u64x2*)(mx1), m1b = *(const u64x2*)(mx1 + 2);
  kp += 64*DMODEL; vp += 64;
  *(bf16x8*)(L + sd[0]) = kr0;  *(bf16x8*)(L + sd[1]) = kr1;
  *(bf16x8*)(L + 8192 + sd[0]) = vr0;  *(bf16x8*)(L + 8192 + sd[1]) = vr1;
  __syncthreads();

  for (int it = 0; it < 32; ++it) {
    u64x2 n0a = {0,0}, n0b = {0,0}, n1a = {0,0}, n1b = {0,0};
    if (it < 31) {
      // issue next-tile loads into regs (latency hides under compute below)
      kr0 = *(const bf16x8*)(kp + ko[0]); kr1 = *(const bf16x8*)(kp + ko[1]);
      vr0 = *(const bf16x8*)(vp + vo[0]); vr1 = *(const bf16x8*)(vp + vo[1]);
      n0a = *(const u64x2*)(mx0 + (it+1)*16);
      n0b = *(const u64x2*)(mx0 + (it+1)*16 + 2);
      n1a = *(const u64x2*)(mx1 + (it+1)*16);
      n1b = *(const u64x2*)(mx1 + (it+1)*16 + 2);
      kp += 64*DMODEL; vp += 64;
    }

    // ---- S^T = K @ Q^T (per u), C=z4 so no zero-init movs ----
    f32x4 st[2][4];
    __builtin_amdgcn_s_setprio(1);
#pragma unroll
    for (int t = 0; t < 4; ++t) {
      int row = t*16 + lq;
      bf16x8 kf0 = *(const bf16x8*)(L + row*128 + ((g ^ (row & 7)) << 4));
      bf16x8 kf1 = *(const bf16x8*)(L + row*128 + (((4 + g) ^ (row & 7)) << 4));
      st[0][t] = mfma16(kf1, qf[0][1], mfma16(kf0, qf[0][0], z4));
      st[1][t] = mfma16(kf1, qf[1][1], mfma16(kf0, qf[1][0], z4));
    }
    __builtin_amdgcn_s_setprio(0);

    // ---- fixed-scale softmax: P = exp2(s), mask via AND on packed bf16 ----
#pragma unroll
    for (int u = 0; u < 2; ++u) {
      char* pb = myP + (u*16 + lq) * 128;
#pragma unroll
      for (int t = 0; t < 4; ++t) {
        int sl = (((t*2 + (g >> 1)) ^ (lq & 7)) << 4) + ((g & 1) << 3);
        float p0 = st[u][t][0], p1 = st[u][t][1];
        float p2 = st[u][t][2], p3 = st[u][t][3];
        fexp2x4(p0, p1, p2, p3);
        u64 mt = u ? ((t < 2) ? m1a[t & 1] : m1b[t & 1])
                   : ((t < 2) ? m0a[t & 1] : m0b[t & 1]);
        union { unsigned w32[2]; u64 w64; } pw;
        pw.w32[0] = cvtpk(p0, p1);
        pw.w32[1] = cvtpk(p2, p3);
        *(u64*)(pb + sl) = pw.w64 & mt;
      }
    }
    asm volatile("s_waitcnt lgkmcnt(0)" ::: "memory");
    __builtin_amdgcn_sched_barrier(0);

    bf16x8 pf[2][2];
#pragma unroll
    for (int u = 0; u < 2; ++u) {
      char* pb = myP + (u*16 + lq) * 128;
      pf[u][0] = *(const bf16x8*)(pb + (((0 + g) ^ (lq & 7)) << 4));
      pf[u][1] = *(const bf16x8*)(pb + (((4 + g) ^ (lq & 7)) << 4));
    }

    // ---- PV + row-sums via ones-MFMA (C=z4, no init movs) ----
    __builtin_amdgcn_s_setprio(1);
    f32x4 ts0 = mfma16(pf[0][1], ones, mfma16(pf[0][0], ones, z4));
    f32x4 ts1 = mfma16(pf[1][1], ones, mfma16(pf[1][0], ones, z4));
#pragma unroll
    for (int t = 0; t < 4; ++t) {
      int row = t*16 + lq;
#pragma unroll
      for (int hh = 0; hh < 2; ++hh) {
        bf16x8 vf = *(const bf16x8*)(L + 8192 + row*128 + (((hh*4 + g) ^ (row & 7)) << 4));
        Oc[0][t] = mfma16(pf[0][hh], vf, Oc[0][t]);
        Oc[1][t] = mfma16(pf[1][hh], vf, Oc[1][t]);
      }
    }
    __builtin_amdgcn_s_setprio(0);
    lrow[0] += ts0;
    lrow[1] += ts1;

    __syncthreads();   // all waves done reading K/V before overwrite
    if (it < 31) {
      *(bf16x8*)(L + sd[0]) = kr0;  *(bf16x8*)(L + sd[1]) = kr1;
      *(bf16x8*)(L + 8192 + sd[0]) = vr0;  *(bf16x8*)(L + 8192 + sd[1]) = vr1;
    }
    __syncthreads();   // staged writes visible to all waves
    m0a = n0a; m0b = n0b; m1a = n1a; m1b = n1b;
  }

#pragma unroll
  for (int u = 0; u < 2; ++u) {
    float i0 = 1.f / lrow[u][0], i1 = 1.f / lrow[u][1],
          i2 = 1.f / lrow[u][2], i3 = 1.f / lrow[u][3];
#pragma unroll
    for (int t = 0; t < 4; ++t) {
      size_t base = ((size_t)(b*S_LEN + qw + u*16 + g*4) * NHEAD + h) * DHEAD + t*16 + lq;
      Zf[base       ] = Oc[u][t][0] * i0;
      Zf[base + 1024] = Oc[u][t][1] * i1;
      Zf[base + 2048] = Oc[u][t][2] * i2;
      Zf[base + 3072] = Oc[u][t][3] * i3;
    }
  }
}

// ---------------- launch ----------------

extern "C" void kernel_launch(void* const* d_in, const int* in_sizes, int n_in,
                              void* d_out, int out_size, void* d_ws, size_t ws_size,
                              hipStream_t stream) {
  const float* x_q  = (const float*)d_in[0];
  const float* x_kv = (const float*)d_in[1];
  const int*   mask = (const int*)d_in[2];
  const float* W_Q  = (const float*)d_in[3];
  const float* W_K  = (const float*)d_in[4];
  const float* W_V  = (const float*)d_in[5];
  const float* W_O  = (const float*)d_in[6];
  const float* b_Q  = (const float*)d_in[7];
  const float* b_K  = (const float*)d_in[8];
  const float* b_V  = (const float*)d_in[9];
  const float* b_O  = (const float*)d_in[10];

  if (ws_size < 102760448) return;  // need 98 MB scratch

  u16* ws  = (u16*)d_ws;
  u16* XQ  = ws;                 // 8388608 elems (aliased by VT later)
  u16* XKV = XQ  + 8388608;
  u16* WQT = XKV + 8388608;      // 1048576 each
  u16* WKT = WQT + 1048576;
  u16* WVT = WKT + 1048576;
  u16* WOH = WVT + 1048576;
  u16* WOL = WOH + 1048576;
  u16* Qb  = WOL + 1048576;      // 8388608 each
  u16* Kb  = Qb  + 8388608;
  u16* Vb  = Kb  + 8388608;
  u64* Mxp = (u64*)(Vb + 8388608);   // 1048576 u64 = 8MB
  u16* VTp = XQ;                 // alias: XQ dead after Q-GEMM

  float* out = (float*)d_out;
  float* zf  = out + 8388608;

  cvt_f32_bf16<<<2048, 256, 0, stream>>>(x_q,  XQ,  2097152);
  cvt_f32_bf16<<<2048, 256, 0, stream>>>(x_kv, XKV, 2097152);
  repack_w<<<dim3(16,16), 256, 0, stream>>>(W_Q, WQT, SC2);
  repack_w<<<dim3(16,16), 256, 0, stream>>>(W_K, WKT, 1.0f);
  repack_w<<<dim3(16,16), 256, 0, stream>>>(W_V, WVT, 1.0f);
  split_wo<<<dim3(16,16), 256, 0, stream>>>(W_O, WOH, WOL);
  mask_expand<<<4096, 256, 0, stream>>>(mask, Mxp);
  gemm_bt<1><<<dim3(8,64), 256, 0, stream>>>(XQ,  WQT, b_Q, SC2, Qb);
  gemm_bt<1><<<dim3(8,64), 256, 0, stream>>>(XKV, WKT, b_K, 1.0f, Kb);
  gemm_bt<1><<<dim3(8,64), 256, 0, stream>>>(XKV, WVT, b_V, 1.0f, Vb);
  transpose_v<<<dim3(32,64), 256, 0, stream>>>(Vb, VTp);
  attn<<<1024, 256, 0, stream>>>(Qb, Kb, VTp, Mxp, zf);
  gemm_out<<<dim3(8,64), 256, 0, stream>>>(zf, WOH, WOL, b_O, out);
}

// Round 10
// 322.758 us; speedup vs baseline: 1.7008x; 1.7008x over previous
//
#include <hip/hip_runtime.h>

#define S_LEN 2048
#define NHEAD 16
#define DHEAD 64
#define DMODEL 1024
#define BATCH 4
#define SC2 0.18033688011112042f   // 0.125 * log2(e)

typedef short bf16x8 __attribute__((ext_vector_type(8)));
typedef float f32x4 __attribute__((ext_vector_type(4)));
typedef unsigned short u16;
typedef unsigned short u16x8 __attribute__((ext_vector_type(8)));
typedef unsigned short u16x4 __attribute__((ext_vector_type(4)));
typedef unsigned long long u64;
typedef unsigned long long u64x2 __attribute__((ext_vector_type(2)));

__device__ __forceinline__ u16 f2b(float f) {
  unsigned u = __builtin_bit_cast(unsigned, f);
  u += 0x7FFFu + ((u >> 16) & 1u);   // RTNE
  return (u16)(u >> 16);
}
__device__ __forceinline__ float b2f(u16 v) {
  unsigned u = ((unsigned)v) << 16;
  return __builtin_bit_cast(float, u);
}
__device__ __forceinline__ f32x4 mfma16(bf16x8 a, bf16x8 b, f32x4 c) {
  return __builtin_amdgcn_mfma_f32_16x16x32_bf16(a, b, c, 0, 0, 0);
}
__device__ __forceinline__ void load_lds16(const void* g, void* l) {
  __builtin_amdgcn_global_load_lds(
      (const __attribute__((address_space(1))) unsigned int*)g,
      (__attribute__((address_space(3))) unsigned int*)l, 16, 0, 0);
}
// Batched raw v_exp_f32 (= 2^x exactly); trailing s_nop covers TRANS hazard.
__device__ __forceinline__ void fexp2x4(float& a, float& b, float& c, float& d) {
  asm("v_exp_f32 %0, %0\n\t"
      "v_exp_f32 %1, %1\n\t"
      "v_exp_f32 %2, %2\n\t"
      "v_exp_f32 %3, %3\n\t"
      "s_nop 1"
      : "+v"(a), "+v"(b), "+v"(c), "+v"(d));
}
__device__ __forceinline__ unsigned cvtpk(float lo, float hi) {
  unsigned r;
  asm("v_cvt_pk_bf16_f32 %0, %1, %2" : "=v"(r) : "v"(lo), "v"(hi));
  return r;
}

// ---------------- prepass kernels ----------------

__global__ void cvt_f32_bf16(const float* __restrict__ src, u16* __restrict__ dst, int n4) {
  int i = blockIdx.x * 256 + threadIdx.x;
  int stride = gridDim.x * 256;
  for (; i < n4; i += stride) {
    float4 v = ((const float4*)src)[i];
    u16x4 o = { f2b(v.x), f2b(v.y), f2b(v.z), f2b(v.w) };
    ((u16x4*)dst)[i] = o;
  }
}

// mask [2048 q][2048 k] int -> Mex[(q*32+T)*16 + g*4 + t] u64 halfword AND-mask
// halfword r covers k = T*64 + t*16 + g*4 + r : 0xFFFF keep, 0 drop.
__global__ void mask_expand(const int* __restrict__ M, u64* __restrict__ Mex) {
  int idx = blockIdx.x * 256 + threadIdx.x;     // 1M groups of 4 elements
  int q = idx >> 9, k = (idx & 511) * 4;
  int4 v = *(const int4*)(M + (size_t)q * S_LEN + k);
  int T = k >> 6, t = (k >> 4) & 3, g = (k >> 2) & 3;
  u64 m = 0;
  if (!v.x) m |= 0xFFFFull;
  if (!v.y) m |= 0xFFFF0000ull;
  if (!v.z) m |= 0xFFFF00000000ull;
  if (!v.w) m |= 0xFFFF000000000000ull;
  Mex[((size_t)q * 32 + T) * 16 + g * 4 + t] = m;
}

// W [16][1024][64] f32 -> WT [1024 c][1024 d] bf16, c = n*64+h, scaled
__global__ void repack_w(const float* __restrict__ W, u16* __restrict__ WT, float scale) {
  __shared__ u16 t[64][66];
  const int tid = threadIdx.x;
  const int n = blockIdx.y, d0 = blockIdx.x * 64;
  const float* src = W + (size_t)n * 65536;
  for (int p = 0; p < 4; ++p) {
    int idx = p * 256 + tid;
    int r = idx >> 4, cs = idx & 15;
    float4 v = *(const float4*)(src + (size_t)(d0 + r) * 64 + cs * 4);
    t[r][cs*4+0] = f2b(v.x*scale); t[r][cs*4+1] = f2b(v.y*scale);
    t[r][cs*4+2] = f2b(v.z*scale); t[r][cs*4+3] = f2b(v.w*scale);
  }
  __syncthreads();
  for (int p = 0; p < 2; ++p) {
    int idx = p * 256 + tid;
    int hl = idx >> 3, ds = idx & 7;
    u16x8 o;
    for (int e = 0; e < 8; ++e) o[e] = t[ds*8+e][hl];
    *(u16x8*)(WT + (size_t)(n*64 + hl) * 1024 + d0 + ds*8) = o;
  }
}

// W_O [1024 c][1024 d] f32 -> WoT hi/lo [1024 d][1024 c] bf16
__global__ void split_wo(const float* __restrict__ Wo, u16* __restrict__ Hi, u16* __restrict__ Lo) {
  __shared__ u16 th[64][66];
  __shared__ u16 tl[64][66];
  const int tid = threadIdx.x;
  const int d0 = blockIdx.x * 64, c0 = blockIdx.y * 64;
  for (int p = 0; p < 4; ++p) {
    int idx = p * 256 + tid;
    int r = idx >> 4, cs = idx & 15;
    float4 v = *(const float4*)(Wo + (size_t)(c0 + r) * 1024 + d0 + cs * 4);
    float f[4] = {v.x, v.y, v.z, v.w};
    for (int e = 0; e < 4; ++e) {
      u16 hb = f2b(f[e]);
      th[r][cs*4+e] = hb;
      tl[r][cs*4+e] = f2b(f[e] - b2f(hb));
    }
  }
  __syncthreads();
  for (int p = 0; p < 2; ++p) {
    int idx = p * 256 + tid;
    int dr = idx >> 3, cs = idx & 7;
    u16x8 oh, ol;
    for (int e = 0; e < 8; ++e) { oh[e] = th[cs*8+e][dr]; ol[e] = tl[cs*8+e][dr]; }
    *(u16x8*)(Hi + (size_t)(d0 + dr) * 1024 + c0 + cs*8) = oh;
    *(u16x8*)(Lo + (size_t)(d0 + dr) * 1024 + c0 + cs*8) = ol;
  }
}

// v [8192][1024] bf16 -> VT [(b*16+h)*64 + dh][2048 s] bf16
__global__ void transpose_v(const u16* __restrict__ V, u16* __restrict__ VT) {
  __shared__ u16 t[64][66];
  const int tid = threadIdx.x;
  const int s0 = blockIdx.x * 64;
  const int b = blockIdx.y >> 4, h = blockIdx.y & 15;
  for (int p = 0; p < 2; ++p) {
    int idx = p * 256 + tid;
    int r = idx >> 3, sg = idx & 7;
    u16x8 v = *(const u16x8*)(V + (size_t)(b*S_LEN + s0 + r) * 1024 + h*64 + sg*8);
    for (int e = 0; e < 8; ++e) t[r][sg*8+e] = v[e];
  }
  __syncthreads();
  for (int p = 0; p < 2; ++p) {
    int idx = p * 256 + tid;
    int dr = idx >> 3, ss = idx & 7;
    u16x8 o;
    for (int e = 0; e < 8; ++e) o[e] = t[ss*8+e][dr];
    *(u16x8*)(VT + ((size_t)(b*NHEAD + h) * 64 + dr) * 2048 + s0 + ss*8) = o;
  }
}

// ---------------- GEMM: C[M][1024] = A[M][1024] * Bt[1024][1024]^T + bias*bscale ----------------

template<int BF16OUT>
__global__ __launch_bounds__(256, 2)
void gemm_bt(const u16* __restrict__ A, const u16* __restrict__ Bt,
             const float* __restrict__ bias, float bscale, void* __restrict__ Cout)
{
  __shared__ __align__(16) char As[16384];
  __shared__ __align__(16) char Bs[16384];
  const int tid = threadIdx.x, wid = tid >> 6, lane = tid & 63;
  const int lq = lane & 15, g = lane >> 4;
  const size_t am0 = (size_t)blockIdx.y * 128;
  const size_t bn0 = (size_t)blockIdx.x * 128;
  const int wr = (wid >> 1) * 64, wc = (wid & 1) * 64;
  f32x4 z4 = {0.f, 0.f, 0.f, 0.f};
  f32x4 acc[4][4];
  for (int i = 0; i < 4; ++i) for (int j = 0; j < 4; ++j) acc[i][j] = z4;
  for (int k0 = 0; k0 < DMODEL; k0 += 64) {
#pragma unroll
    for (int c = 0; c < 4; ++c) {
      int idx = c*256 + tid, r = idx >> 3, s = idx & 7;
      load_lds16(A + (am0 + r)*DMODEL + k0 + ((s ^ (r & 7)) << 3), As + idx*16);
    }
#pragma unroll
    for (int c = 0; c < 4; ++c) {
      int idx = c*256 + tid, r = idx >> 3, s = idx & 7;
      load_lds16(Bt + (bn0 + r)*DMODEL + k0 + ((s ^ (r & 7)) << 3), Bs + idx*16);
    }
    __syncthreads();
#pragma unroll
    for (int ks = 0; ks < 2; ++ks) {
      bf16x8 af[4], bfr[4];
#pragma unroll
      for (int i = 0; i < 4; ++i) {
        int row = wr + i*16 + lq;
        af[i] = *(const bf16x8*)(As + row*128 + (((ks*4 + g) ^ (row & 7)) << 4));
      }
#pragma unroll
      for (int j = 0; j < 4; ++j) {
        int row = wc + j*16 + lq;
        bfr[j] = *(const bf16x8*)(Bs + row*128 + (((ks*4 + g) ^ (row & 7)) << 4));
      }
#pragma unroll
      for (int i = 0; i < 4; ++i)
#pragma unroll
        for (int j = 0; j < 4; ++j)
          acc[i][j] = mfma16(af[i], bfr[j], acc[i][j]);
    }
    __syncthreads();
  }
#pragma unroll
  for (int i = 0; i < 4; ++i)
#pragma unroll
    for (int j = 0; j < 4; ++j) {
      size_t row = am0 + wr + i*16 + g*4;
      int col = (int)bn0 + wc + j*16 + lq;
      float bv = bias[col] * bscale;
#pragma unroll
      for (int r = 0; r < 4; ++r) {
        float v = acc[i][j][r] + bv;
        if (BF16OUT) ((u16*)Cout)[(row + r)*DMODEL + col] = f2b(v);
        else         ((float*)Cout)[(row + r)*DMODEL + col] = v;
      }
    }
}

// ---------------- out = Z(f32, split hi/lo) @ WoT^T + b_O ----------------

__global__ __launch_bounds__(256, 2)
void gemm_out(const float* __restrict__ Z, const u16* __restrict__ Bh,
              const u16* __restrict__ Bl, const float* __restrict__ bias,
              float* __restrict__ Cout)
{
  __shared__ __align__(16) char Ah[16384];
  __shared__ __align__(16) char Al[16384];
  __shared__ __align__(16) char Bhs[16384];
  __shared__ __align__(16) char Bls[16384];
  const int tid = threadIdx.x, wid = tid >> 6, lane = tid & 63;
  const int lq = lane & 15, g = lane >> 4;
  const size_t am0 = (size_t)blockIdx.y * 128;
  const size_t bn0 = (size_t)blockIdx.x * 128;
  const int wr = (wid >> 1) * 64, wc = (wid & 1) * 64;
  f32x4 z4 = {0.f, 0.f, 0.f, 0.f};
  f32x4 acc[4][4];
  for (int i = 0; i < 4; ++i) for (int j = 0; j < 4; ++j) acc[i][j] = z4;
  for (int k0 = 0; k0 < DMODEL; k0 += 64) {
#pragma unroll
    for (int c = 0; c < 8; ++c) {
      int idx = c*256 + tid, r = idx >> 4, fs = idx & 15;
      float4 v = *(const float4*)(Z + (am0 + r)*DMODEL + k0 + fs*4);
      float f[4] = {v.x, v.y, v.z, v.w};
      u16x4 hv, lv;
      for (int e = 0; e < 4; ++e) {
        u16 hb = f2b(f[e]);
        hv[e] = hb;
        lv[e] = f2b(f[e] - b2f(hb));
      }
      int byo = r*128 + ((((fs >> 1) ^ (r & 7)) << 4) | ((fs & 1) << 3));
      *(u16x4*)(Ah + byo) = hv;
      *(u16x4*)(Al + byo) = lv;
    }
#pragma unroll
    for (int c = 0; c < 4; ++c) {
      int idx = c*256 + tid, r = idx >> 3, s = idx & 7;
      load_lds16(Bh + (bn0 + r)*DMODEL + k0 + ((s ^ (r & 7)) << 3), Bhs + idx*16);
    }
#pragma unroll
    for (int c = 0; c < 4; ++c) {
      int idx = c*256 + tid, r = idx >> 3, s = idx & 7;
      load_lds16(Bl + (bn0 + r)*DMODEL + k0 + ((s ^ (r & 7)) << 3), Bls + idx*16);
    }
    __syncthreads();
#pragma unroll
    for (int ks = 0; ks < 2; ++ks) {
      bf16x8 ah[4], al[4], bh4[4], bl4[4];
#pragma unroll
      for (int i = 0; i < 4; ++i) {
        int row = wr + i*16 + lq;
        int off = row*128 + (((ks*4 + g) ^ (row & 7)) << 4);
        ah[i] = *(const bf16x8*)(Ah + off);
        al[i] = *(const bf16x8*)(Al + off);
      }
#pragma unroll
      for (int j = 0; j < 4; ++j) {
        int row = wc + j*16 + lq;
        int off = row*128 + (((ks*4 + g) ^ (row & 7)) << 4);
        bh4[j] = *(const bf16x8*)(Bhs + off);
        bl4[j] = *(const bf16x8*)(Bls + off);
      }
#pragma unroll
      for (int i = 0; i < 4; ++i)
#pragma unroll
        for (int j = 0; j < 4; ++j) {
          acc[i][j] = mfma16(al[i], bh4[j], acc[i][j]);
          acc[i][j] = mfma16(ah[i], bl4[j], acc[i][j]);
          acc[i][j] = mfma16(ah[i], bh4[j], acc[i][j]);
        }
    }
    __syncthreads();
  }
#pragma unroll
  for (int i = 0; i < 4; ++i)
#pragma unroll
    for (int j = 0; j < 4; ++j) {
      size_t row = am0 + wr + i*16 + g*4;
      int col = (int)bn0 + wc + j*16 + lq;
      float bv = bias[col];
#pragma unroll
      for (int r = 0; r < 4; ++r)
        Cout[(row + r)*DMODEL + col] = acc[i][j][r] + bv;
    }
}

// ---------------- flash attention ----------------
// grid 1024 blocks (XCD-swizzled (qt,h,b)), 256 threads = 4 waves x 32 q-rows
// LDS 40KB: K/V double-buffer @ {0,16384} (K 8K | V 8K each); P @32768:
// per-wave 2KB reused for u=0 then u=1.
// K/V staged via global_load_lds (no staging regs); masks loaded per-iter.
// launch_bounds(256,4): needs arch+acc <= 128 regs -> 4 blocks/CU.
__global__ __launch_bounds__(256, 4)
void attn(const u16* __restrict__ Q, const u16* __restrict__ K,
          const u16* __restrict__ VT, const u64* __restrict__ Mex,
          float* __restrict__ Zf)
{
  __shared__ __align__(16) char L[40960];
  const int tid = threadIdx.x, wid = tid >> 6, lane = tid & 63;
  const int lq = lane & 15, g = lane >> 4;
  // XCD swizzle: all 16 q-tile blocks of one (b,h) on one XCD (round-robin %8)
  const int Lb = blockIdx.x;
  const int xcd = Lb & 7, slot = Lb >> 3;
  const int qt = slot & 15, pl = slot >> 4;
  const int pair = xcd * 8 + pl;          // 0..63
  const int h = pair & 15, b = pair >> 4;
  const int q0 = qt * 128;
  const int qw = q0 + wid * 32;

  bf16x8 qf[2][2];
#pragma unroll
  for (int u = 0; u < 2; ++u) {
    const u16* qp = Q + (size_t)(b*S_LEN + qw + u*16 + lq) * DMODEL + h*DHEAD + g*8;
    qf[u][0] = *(const bf16x8*)qp;
    qf[u][1] = *(const bf16x8*)(qp + 32);
  }
  bf16x8 ones;
#pragma unroll
  for (int e = 0; e < 8; ++e) ones[e] = (short)0x3F80;

  const f32x4 z4 = {0.f, 0.f, 0.f, 0.f};
  f32x4 Oc[2][4];
#pragma unroll
  for (int u = 0; u < 2; ++u)
#pragma unroll
    for (int t = 0; t < 4; ++t) Oc[u][t] = z4;
  f32x4 lrow[2] = {z4, z4};

  const u16* kp = K + (size_t)(b*S_LEN)*DMODEL + h*DHEAD;
  const u16* vp = VT + (size_t)((b*NHEAD + h)*DHEAD)*S_LEN;
  const u64* mx0 = Mex + (size_t)(qw + lq) * 512 + g*4;        // u=0 row
  const u64* mx1 = Mex + (size_t)(qw + 16 + lq) * 512 + g*4;   // u=1 row
  char* myP = L + 32768 + wid*2048;

  // per-thread staging offsets (pre-swizzled global sources, linear LDS dests)
  size_t ko[2], vo[2];
  int sd[2];
#pragma unroll
  for (int c = 0; c < 2; ++c) {
    int idx = c*256 + tid, r = idx >> 3, s = idx & 7, so = (s ^ (r & 7)) << 3;
    ko[c] = (size_t)r * DMODEL + so;
    vo[c] = (size_t)r * S_LEN + so;
    sd[c] = idx * 16;
  }

#define STAGE(Bb) do { \
    load_lds16(kp + ko[0], (Bb) + sd[0]); \
    load_lds16(kp + ko[1], (Bb) + sd[1]); \
    load_lds16(vp + vo[0], (Bb) + 8192 + sd[0]); \
    load_lds16(vp + vo[1], (Bb) + 8192 + sd[1]); \
    kp += 64*DMODEL; vp += 64; \
  } while (0)

  STAGE(L);
  __syncthreads();

  for (int it = 0; it < 32; ++it) {
    char* Bu = L + (it & 1) * 16384;
    if (it < 31) STAGE(L + ((it + 1) & 1) * 16384);

    // current-iter masks (L2-resident; latency covered by QK phase)
    u64x2 m0a = *(const u64x2*)(mx0 + it*16);
    u64x2 m0b = *(const u64x2*)(mx0 + it*16 + 2);
    u64x2 m1a = *(const u64x2*)(mx1 + it*16);
    u64x2 m1b = *(const u64x2*)(mx1 + it*16 + 2);

    // ---- S^T = K @ Q^T (per u), C=z4 so no zero-init movs ----
    f32x4 st[2][4];
    __builtin_amdgcn_s_setprio(1);
#pragma unroll
    for (int t = 0; t < 4; ++t) {
      int row = t*16 + lq;
      bf16x8 kf0 = *(const bf16x8*)(Bu + row*128 + ((g ^ (row & 7)) << 4));
      bf16x8 kf1 = *(const bf16x8*)(Bu + row*128 + (((4 + g) ^ (row & 7)) << 4));
      st[0][t] = mfma16(kf1, qf[0][1], mfma16(kf0, qf[0][0], z4));
      st[1][t] = mfma16(kf1, qf[1][1], mfma16(kf0, qf[1][0], z4));
    }
    __builtin_amdgcn_s_setprio(0);

    // ---- fixed-scale softmax: P = exp2(s), mask via AND on packed bf16.
    //      P buffer (2KB/wave) reused: u=0 write+read, then u=1. ----
    bf16x8 pf[2][2];
#pragma unroll
    for (int u = 0; u < 2; ++u) {
      char* pb = myP + lq * 128;
#pragma unroll
      for (int t = 0; t < 4; ++t) {
        int sl = (((t*2 + (g >> 1)) ^ (lq & 7)) << 4) + ((g & 1) << 3);
        float p0 = st[u][t][0], p1 = st[u][t][1];
        float p2 = st[u][t][2], p3 = st[u][t][3];
        fexp2x4(p0, p1, p2, p3);
        u64 mt = u ? ((t < 2) ? m1a[t & 1] : m1b[t & 1])
                   : ((t < 2) ? m0a[t & 1] : m0b[t & 1]);
        union { unsigned w32[2]; u64 w64; } pw;
        pw.w32[0] = cvtpk(p0, p1);
        pw.w32[1] = cvtpk(p2, p3);
        *(u64*)(pb + sl) = pw.w64 & mt;
      }
      asm volatile("s_waitcnt lgkmcnt(0)" ::: "memory");
      __builtin_amdgcn_sched_barrier(0);
      pf[u][0] = *(const bf16x8*)(pb + (((0 + g) ^ (lq & 7)) << 4));
      pf[u][1] = *(const bf16x8*)(pb + (((4 + g) ^ (lq & 7)) << 4));
      asm volatile("s_waitcnt lgkmcnt(0)" ::: "memory");
      __builtin_amdgcn_sched_barrier(0);   // reads land before u=1 overwrites
    }

    // ---- PV + row-sums via ones-MFMA (C=z4, no init movs) ----
    __builtin_amdgcn_s_setprio(1);
    f32x4 ts0 = mfma16(pf[0][1], ones, mfma16(pf[0][0], ones, z4));
    f32x4 ts1 = mfma16(pf[1][1], ones, mfma16(pf[1][0], ones, z4));
#pragma unroll
    for (int t = 0; t < 4; ++t) {
      int row = t*16 + lq;
#pragma unroll
      for (int hh = 0; hh < 2; ++hh) {
        bf16x8 vf = *(const bf16x8*)(Bu + 8192 + row*128 + (((hh*4 + g) ^ (row & 7)) << 4));
        Oc[0][t] = mfma16(pf[0][hh], vf, Oc[0][t]);
        Oc[1][t] = mfma16(pf[1][hh], vf, Oc[1][t]);
      }
    }
    __builtin_amdgcn_s_setprio(0);
    lrow[0] += ts0;
    lrow[1] += ts1;

    // single barrier per iter: drains staging vmcnt, publishes next buffer,
    // and protects the buffer being overwritten next iter.
    __syncthreads();
  }
#undef STAGE

#pragma unroll
  for (int u = 0; u < 2; ++u) {
    float i0 = 1.f / lrow[u][0], i1 = 1.f / lrow[u][1],
          i2 = 1.f / lrow[u][2], i3 = 1.f / lrow[u][3];
#pragma unroll
    for (int t = 0; t < 4; ++t) {
      size_t base = ((size_t)(b*S_LEN + qw + u*16 + g*4) * NHEAD + h) * DHEAD + t*16 + lq;
      Zf[base       ] = Oc[u][t][0] * i0;
      Zf[base + 1024] = Oc[u][t][1] * i1;
      Zf[base + 2048] = Oc[u][t][2] * i2;
      Zf[base + 3072] = Oc[u][t][3] * i3;
    }
  }
}

// ---------------- launch ----------------

extern "C" void kernel_launch(void* const* d_in, const int* in_sizes, int n_in,
                              void* d_out, int out_size, void* d_ws, size_t ws_size,
                              hipStream_t stream) {
  const float* x_q  = (const float*)d_in[0];
  const float* x_kv = (const float*)d_in[1];
  const int*   mask = (const int*)d_in[2];
  const float* W_Q  = (const float*)d_in[3];
  const float* W_K  = (const float*)d_in[4];
  const float* W_V  = (const float*)d_in[5];
  const float* W_O  = (const float*)d_in[6];
  const float* b_Q  = (const float*)d_in[7];
  const float* b_K  = (const float*)d_in[8];
  const float* b_V  = (const float*)d_in[9];
  const float* b_O  = (const float*)d_in[10];

  if (ws_size < 102760448) return;  // need 98 MB scratch

  u16* ws  = (u16*)d_ws;
  u16* XQ  = ws;                 // 8388608 elems (aliased by VT later)
  u16* XKV = XQ  + 8388608;
  u16* WQT = XKV + 8388608;      // 1048576 each
  u16* WKT = WQT + 1048576;
  u16* WVT = WKT + 1048576;
  u16* WOH = WVT + 1048576;
  u16* WOL = WOH + 1048576;
  u16* Qb  = WOL + 1048576;      // 8388608 each
  u16* Kb  = Qb  + 8388608;
  u16* Vb  = Kb  + 8388608;
  u64* Mxp = (u64*)(Vb + 8388608);   // 1048576 u64 = 8MB
  u16* VTp = XQ;                 // alias: XQ dead after Q-GEMM

  float* out = (float*)d_out;
  float* zf  = out + 8388608;

  cvt_f32_bf16<<<2048, 256, 0, stream>>>(x_q,  XQ,  2097152);
  cvt_f32_bf16<<<2048, 256, 0, stream>>>(x_kv, XKV, 2097152);
  repack_w<<<dim3(16,16), 256, 0, stream>>>(W_Q, WQT, SC2);
  repack_w<<<dim3(16,16), 256, 0, stream>>>(W_K, WKT, 1.0f);
  repack_w<<<dim3(16,16), 256, 0, stream>>>(W_V, WVT, 1.0f);
  split_wo<<<dim3(16,16), 256, 0, stream>>>(W_O, WOH, WOL);
  mask_expand<<<4096, 256, 0, stream>>>(mask, Mxp);
  gemm_bt<1><<<dim3(8,64), 256, 0, stream>>>(XQ,  WQT, b_Q, SC2, Qb);
  gemm_bt<1><<<dim3(8,64), 256, 0, stream>>>(XKV, WKT, b_K, 1.0f, Kb);
  gemm_bt<1><<<dim3(8,64), 256, 0, stream>>>(XKV, WVT, b_V, 1.0f, Vb);
  transpose_v<<<dim3(32,64), 256, 0, stream>>>(Vb, VTp);
  attn<<<1024, 256, 0, stream>>>(Qb, Kb, VTp, Mxp, zf);
  gemm_out<<<dim3(8,64), 256, 0, stream>>>(zf, WOH, WOL, b_O, out);
}

// Round 11
// 257.522 us; speedup vs baseline: 2.1317x; 1.2533x over previous
//
#include <hip/hip_runtime.h>

#define S_LEN 2048
#define NHEAD 16
#define DHEAD 64
#define DMODEL 1024
#define BATCH 4
#define SC2 0.18033688011112042f   // 0.125 * log2(e)

typedef short bf16x8 __attribute__((ext_vector_type(8)));
typedef float f32x4 __attribute__((ext_vector_type(4)));
typedef unsigned short u16;
typedef unsigned short u16x8 __attribute__((ext_vector_type(8)));
typedef unsigned short u16x4 __attribute__((ext_vector_type(4)));
typedef unsigned long long u64;
typedef unsigned long long u64x2 __attribute__((ext_vector_type(2)));

__device__ __forceinline__ u16 f2b(float f) {
  unsigned u = __builtin_bit_cast(unsigned, f);
  u += 0x7FFFu + ((u >> 16) & 1u);   // RTNE
  return (u16)(u >> 16);
}
__device__ __forceinline__ float b2f(u16 v) {
  unsigned u = ((unsigned)v) << 16;
  return __builtin_bit_cast(float, u);
}
__device__ __forceinline__ f32x4 mfma16(bf16x8 a, bf16x8 b, f32x4 c) {
  return __builtin_amdgcn_mfma_f32_16x16x32_bf16(a, b, c, 0, 0, 0);
}
__device__ __forceinline__ void load_lds16(const void* g, void* l) {
  __builtin_amdgcn_global_load_lds(
      (const __attribute__((address_space(1))) unsigned int*)g,
      (__attribute__((address_space(3))) unsigned int*)l, 16, 0, 0);
}
// Batched raw v_exp_f32 (= 2^x exactly); trailing s_nop covers TRANS hazard.
__device__ __forceinline__ void fexp2x4(float& a, float& b, float& c, float& d) {
  asm("v_exp_f32 %0, %0\n\t"
      "v_exp_f32 %1, %1\n\t"
      "v_exp_f32 %2, %2\n\t"
      "v_exp_f32 %3, %3\n\t"
      "s_nop 1"
      : "+v"(a), "+v"(b), "+v"(c), "+v"(d));
}
__device__ __forceinline__ unsigned cvtpk(float lo, float hi) {
  unsigned r;
  asm("v_cvt_pk_bf16_f32 %0, %1, %2" : "=v"(r) : "v"(lo), "v"(hi));
  return r;
}

// ---------------- merged prepass: cvt x_q, cvt x_kv, mask_expand ----------------

__global__ void prepass(const float* __restrict__ xq, const float* __restrict__ xkv,
                        const int* __restrict__ M,
                        u16* __restrict__ XQ, u16* __restrict__ XKV,
                        u64* __restrict__ Mex)
{
  int i = blockIdx.x * 256 + threadIdx.x;
  int stride = gridDim.x * 256;
  for (; i < 5242880; i += stride) {
    if (i < 2097152) {
      float4 v = ((const float4*)xq)[i];
      u16x4 o = { f2b(v.x), f2b(v.y), f2b(v.z), f2b(v.w) };
      ((u16x4*)XQ)[i] = o;
    } else if (i < 4194304) {
      int j = i - 2097152;
      float4 v = ((const float4*)xkv)[j];
      u16x4 o = { f2b(v.x), f2b(v.y), f2b(v.z), f2b(v.w) };
      ((u16x4*)XKV)[j] = o;
    } else {
      int idx = i - 4194304;                 // 1M groups of 4 mask elements
      int q = idx >> 9, k = (idx & 511) * 4;
      int4 v = *(const int4*)(M + (size_t)q * S_LEN + k);
      int T = k >> 6, t = (k >> 4) & 3, g = (k >> 2) & 3;
      u64 m = 0;
      if (!v.x) m |= 0xFFFFull;
      if (!v.y) m |= 0xFFFF0000ull;
      if (!v.z) m |= 0xFFFF00000000ull;
      if (!v.w) m |= 0xFFFF000000000000ull;
      Mex[((size_t)q * 32 + T) * 16 + g * 4 + t] = m;
    }
  }
}

// W [16][1024][64] f32 -> WT [1024 c][1024 d] bf16, c = n*64+h; 3 matrices in z
__global__ void repack_w3(const float* __restrict__ WQ, const float* __restrict__ WK,
                          const float* __restrict__ WV,
                          u16* __restrict__ WQT, u16* __restrict__ WKT,
                          u16* __restrict__ WVT)
{
  __shared__ u16 t[64][66];
  const int which = blockIdx.z;
  const float* W = which == 0 ? WQ : (which == 1 ? WK : WV);
  u16* WT = which == 0 ? WQT : (which == 1 ? WKT : WVT);
  const float scale = which == 0 ? SC2 : 1.0f;
  const int tid = threadIdx.x;
  const int n = blockIdx.y, d0 = blockIdx.x * 64;
  const float* src = W + (size_t)n * 65536;
  for (int p = 0; p < 4; ++p) {
    int idx = p * 256 + tid;
    int r = idx >> 4, cs = idx & 15;
    float4 v = *(const float4*)(src + (size_t)(d0 + r) * 64 + cs * 4);
    t[r][cs*4+0] = f2b(v.x*scale); t[r][cs*4+1] = f2b(v.y*scale);
    t[r][cs*4+2] = f2b(v.z*scale); t[r][cs*4+3] = f2b(v.w*scale);
  }
  __syncthreads();
  for (int p = 0; p < 2; ++p) {
    int idx = p * 256 + tid;
    int hl = idx >> 3, ds = idx & 7;
    u16x8 o;
    for (int e = 0; e < 8; ++e) o[e] = t[ds*8+e][hl];
    *(u16x8*)(WT + (size_t)(n*64 + hl) * 1024 + d0 + ds*8) = o;
  }
}

// W_O [1024 c][1024 d] f32 -> WoT hi/lo [1024 d][1024 c] bf16
__global__ void split_wo(const float* __restrict__ Wo, u16* __restrict__ Hi, u16* __restrict__ Lo) {
  __shared__ u16 th[64][66];
  __shared__ u16 tl[64][66];
  const int tid = threadIdx.x;
  const int d0 = blockIdx.x * 64, c0 = blockIdx.y * 64;
  for (int p = 0; p < 4; ++p) {
    int idx = p * 256 + tid;
    int r = idx >> 4, cs = idx & 15;
    float4 v = *(const float4*)(Wo + (size_t)(c0 + r) * 1024 + d0 + cs * 4);
    float f[4] = {v.x, v.y, v.z, v.w};
    for (int e = 0; e < 4; ++e) {
      u16 hb = f2b(f[e]);
      th[r][cs*4+e] = hb;
      tl[r][cs*4+e] = f2b(f[e] - b2f(hb));
    }
  }
  __syncthreads();
  for (int p = 0; p < 2; ++p) {
    int idx = p * 256 + tid;
    int dr = idx >> 3, cs = idx & 7;
    u16x8 oh, ol;
    for (int e = 0; e < 8; ++e) { oh[e] = th[cs*8+e][dr]; ol[e] = tl[cs*8+e][dr]; }
    *(u16x8*)(Hi + (size_t)(d0 + dr) * 1024 + c0 + cs*8) = oh;
    *(u16x8*)(Lo + (size_t)(d0 + dr) * 1024 + c0 + cs*8) = ol;
  }
}

// v [8192][1024] bf16 -> VT [(b*16+h)*64 + dh][2048 s] bf16
__global__ void transpose_v(const u16* __restrict__ V, u16* __restrict__ VT) {
  __shared__ u16 t[64][66];
  const int tid = threadIdx.x;
  const int s0 = blockIdx.x * 64;
  const int b = blockIdx.y >> 4, h = blockIdx.y & 15;
  for (int p = 0; p < 2; ++p) {
    int idx = p * 256 + tid;
    int r = idx >> 3, sg = idx & 7;
    u16x8 v = *(const u16x8*)(V + (size_t)(b*S_LEN + s0 + r) * 1024 + h*64 + sg*8);
    for (int e = 0; e < 8; ++e) t[r][sg*8+e] = v[e];
  }
  __syncthreads();
  for (int p = 0; p < 2; ++p) {
    int idx = p * 256 + tid;
    int dr = idx >> 3, ss = idx & 7;
    u16x8 o;
    for (int e = 0; e < 8; ++e) o[e] = t[ss*8+e][dr];
    *(u16x8*)(VT + ((size_t)(b*NHEAD + h) * 64 + dr) * 2048 + s0 + ss*8) = o;
  }
}

// ---------------- merged QKV GEMM: z selects (A, Bt, bias, scale, C) ----------------

__global__ __launch_bounds__(256, 2)
void gemm_qkv(const u16* __restrict__ XQ, const u16* __restrict__ XKV,
              const u16* __restrict__ WQT, const u16* __restrict__ WKT,
              const u16* __restrict__ WVT,
              const float* __restrict__ bQ, const float* __restrict__ bK,
              const float* __restrict__ bV,
              u16* __restrict__ Qb, u16* __restrict__ Kb, u16* __restrict__ Vb)
{
  const int which = blockIdx.z;
  const u16* A  = which == 0 ? XQ : XKV;
  const u16* Bt = which == 0 ? WQT : (which == 1 ? WKT : WVT);
  const float* bias = which == 0 ? bQ : (which == 1 ? bK : bV);
  const float bscale = which == 0 ? SC2 : 1.0f;
  u16* Cout = which == 0 ? Qb : (which == 1 ? Kb : Vb);

  __shared__ __align__(16) char As[16384];
  __shared__ __align__(16) char Bs[16384];
  const int tid = threadIdx.x, wid = tid >> 6, lane = tid & 63;
  const int lq = lane & 15, g = lane >> 4;
  const size_t am0 = (size_t)blockIdx.y * 128;
  const size_t bn0 = (size_t)blockIdx.x * 128;
  const int wr = (wid >> 1) * 64, wc = (wid & 1) * 64;
  f32x4 z4 = {0.f, 0.f, 0.f, 0.f};
  f32x4 acc[4][4];
  for (int i = 0; i < 4; ++i) for (int j = 0; j < 4; ++j) acc[i][j] = z4;
  for (int k0 = 0; k0 < DMODEL; k0 += 64) {
#pragma unroll
    for (int c = 0; c < 4; ++c) {
      int idx = c*256 + tid, r = idx >> 3, s = idx & 7;
      load_lds16(A + (am0 + r)*DMODEL + k0 + ((s ^ (r & 7)) << 3), As + idx*16);
    }
#pragma unroll
    for (int c = 0; c < 4; ++c) {
      int idx = c*256 + tid, r = idx >> 3, s = idx & 7;
      load_lds16(Bt + (bn0 + r)*DMODEL + k0 + ((s ^ (r & 7)) << 3), Bs + idx*16);
    }
    __syncthreads();
#pragma unroll
    for (int ks = 0; ks < 2; ++ks) {
      bf16x8 af[4], bfr[4];
#pragma unroll
      for (int i = 0; i < 4; ++i) {
        int row = wr + i*16 + lq;
        af[i] = *(const bf16x8*)(As + row*128 + (((ks*4 + g) ^ (row & 7)) << 4));
      }
#pragma unroll
      for (int j = 0; j < 4; ++j) {
        int row = wc + j*16 + lq;
        bfr[j] = *(const bf16x8*)(Bs + row*128 + (((ks*4 + g) ^ (row & 7)) << 4));
      }
#pragma unroll
      for (int i = 0; i < 4; ++i)
#pragma unroll
        for (int j = 0; j < 4; ++j)
          acc[i][j] = mfma16(af[i], bfr[j], acc[i][j]);
    }
    __syncthreads();
  }
#pragma unroll
  for (int i = 0; i < 4; ++i)
#pragma unroll
    for (int j = 0; j < 4; ++j) {
      size_t row = am0 + wr + i*16 + g*4;
      int col = (int)bn0 + wc + j*16 + lq;
      float bv = bias[col] * bscale;
#pragma unroll
      for (int r = 0; r < 4; ++r)
        Cout[(row + r)*DMODEL + col] = f2b(acc[i][j][r] + bv);
    }
}

// ---------------- out = (Zh+Zl) @ WoT^T + b_O  (all bf16 via load_lds) ----------------

__global__ __launch_bounds__(256, 2)
void gemm_out(const u16* __restrict__ Zh, const u16* __restrict__ Zl,
              const u16* __restrict__ Bh, const u16* __restrict__ Bl,
              const float* __restrict__ bias, float* __restrict__ Cout)
{
  __shared__ __align__(16) char Ah[16384];
  __shared__ __align__(16) char Al[16384];
  __shared__ __align__(16) char Bhs[16384];
  __shared__ __align__(16) char Bls[16384];
  const int tid = threadIdx.x, wid = tid >> 6, lane = tid & 63;
  const int lq = lane & 15, g = lane >> 4;
  const size_t am0 = (size_t)blockIdx.y * 128;
  const size_t bn0 = (size_t)blockIdx.x * 128;
  const int wr = (wid >> 1) * 64, wc = (wid & 1) * 64;
  f32x4 z4 = {0.f, 0.f, 0.f, 0.f};
  f32x4 acc[4][4];
  for (int i = 0; i < 4; ++i) for (int j = 0; j < 4; ++j) acc[i][j] = z4;
  for (int k0 = 0; k0 < DMODEL; k0 += 64) {
#pragma unroll
    for (int c = 0; c < 4; ++c) {
      int idx = c*256 + tid, r = idx >> 3, s = idx & 7;
      int so = (s ^ (r & 7)) << 3;
      load_lds16(Zh + (am0 + r)*DMODEL + k0 + so, Ah + idx*16);
      load_lds16(Zl + (am0 + r)*DMODEL + k0 + so, Al + idx*16);
      load_lds16(Bh + (bn0 + r)*DMODEL + k0 + so, Bhs + idx*16);
      load_lds16(Bl + (bn0 + r)*DMODEL + k0 + so, Bls + idx*16);
    }
    __syncthreads();
#pragma unroll
    for (int ks = 0; ks < 2; ++ks) {
      bf16x8 ah[4], al[4], bh4[4], bl4[4];
#pragma unroll
      for (int i = 0; i < 4; ++i) {
        int row = wr + i*16 + lq;
        int off = row*128 + (((ks*4 + g) ^ (row & 7)) << 4);
        ah[i] = *(const bf16x8*)(Ah + off);
        al[i] = *(const bf16x8*)(Al + off);
      }
#pragma unroll
      for (int j = 0; j < 4; ++j) {
        int row = wc + j*16 + lq;
        int off = row*128 + (((ks*4 + g) ^ (row & 7)) << 4);
        bh4[j] = *(const bf16x8*)(Bhs + off);
        bl4[j] = *(const bf16x8*)(Bls + off);
      }
#pragma unroll
      for (int i = 0; i < 4; ++i)
#pragma unroll
        for (int j = 0; j < 4; ++j) {
          acc[i][j] = mfma16(al[i], bh4[j], acc[i][j]);
          acc[i][j] = mfma16(ah[i], bl4[j], acc[i][j]);
          acc[i][j] = mfma16(ah[i], bh4[j], acc[i][j]);
        }
    }
    __syncthreads();
  }
#pragma unroll
  for (int i = 0; i < 4; ++i)
#pragma unroll
    for (int j = 0; j < 4; ++j) {
      size_t row = am0 + wr + i*16 + g*4;
      int col = (int)bn0 + wc + j*16 + lq;
      float bv = bias[col];
#pragma unroll
      for (int r = 0; r < 4; ++r)
        Cout[(row + r)*DMODEL + col] = acc[i][j][r] + bv;
    }
}

// ---------------- flash attention (round-8 verbatim core + Zh/Zl epilogue) ----------------
// grid 1024 blocks (XCD-swizzled (qt,h,b)), 256 threads = 4 waves x 32 q-rows
// LDS 48KB: buf{0,1} @ {0,16384}: K 8K | V 8K ; P @ 32768: per-wave 4K
__global__ __launch_bounds__(256, 3)
void attn(const u16* __restrict__ Q, const u16* __restrict__ K,
          const u16* __restrict__ VT, const u64* __restrict__ Mex,
          float* __restrict__ Zf, u16* __restrict__ Zh, u16* __restrict__ Zl)
{
  __shared__ __align__(16) char L[49152];
  const int tid = threadIdx.x, wid = tid >> 6, lane = tid & 63;
  const int lq = lane & 15, g = lane >> 4;
  const int Lb = blockIdx.x;
  const int xcd = Lb & 7, slot = Lb >> 3;
  const int qt = slot & 15, pl = slot >> 4;
  const int pair = xcd * 8 + pl;          // 0..63
  const int h = pair & 15, b = pair >> 4;
  const int q0 = qt * 128;
  const int qw = q0 + wid * 32;

  bf16x8 qf[2][2];
#pragma unroll
  for (int u = 0; u < 2; ++u) {
    const u16* qp = Q + (size_t)(b*S_LEN + qw + u*16 + lq) * DMODEL + h*DHEAD + g*8;
    qf[u][0] = *(const bf16x8*)qp;
    qf[u][1] = *(const bf16x8*)(qp + 32);
  }
  bf16x8 ones;
#pragma unroll
  for (int e = 0; e < 8; ++e) ones[e] = (short)0x3F80;

  const f32x4 z4 = {0.f, 0.f, 0.f, 0.f};
  f32x4 Oc[2][4];
#pragma unroll
  for (int u = 0; u < 2; ++u)
#pragma unroll
    for (int t = 0; t < 4; ++t) Oc[u][t] = z4;
  f32x4 lrow[2] = {z4, z4};

  const u16* kp = K + (size_t)(b*S_LEN)*DMODEL + h*DHEAD;
  const u16* vp = VT + (size_t)((b*NHEAD + h)*DHEAD)*S_LEN;
  const u64* mx0 = Mex + (size_t)(qw + lq) * 512 + g*4;
  const u64* mx1 = Mex + (size_t)(qw + 16 + lq) * 512 + g*4;
  char* myP = L + 32768 + wid*4096;

  size_t ko[2], vo[2];
  int sd[2];
#pragma unroll
  for (int c = 0; c < 2; ++c) {
    int idx = c*256 + tid, r = idx >> 3, s = idx & 7, so = (s ^ (r & 7)) << 3;
    ko[c] = (size_t)r * DMODEL + so;
    vo[c] = (size_t)r * S_LEN + so;
    sd[c] = idx * 16;
  }

  // ---- prologue: tile 0 ----
  bf16x8 kr0, kr1, vr0, vr1;
  kr0 = *(const bf16x8*)(kp + ko[0]); kr1 = *(const bf16x8*)(kp + ko[1]);
  vr0 = *(const bf16x8*)(vp + vo[0]); vr1 = *(const bf16x8*)(vp + vo[1]);
  u64x2 m0a = *(const u64x2*)(mx0), m0b = *(const u64x2*)(mx0 + 2);
  u64x2 m1a = *(const u64x2*)(mx1), m1b = *(const u64x2*)(mx1 + 2);
  kp += 64*DMODEL; vp += 64;
  *(bf16x8*)(L + sd[0]) = kr0;  *(bf16x8*)(L + sd[1]) = kr1;
  *(bf16x8*)(L + 8192 + sd[0]) = vr0;  *(bf16x8*)(L + 8192 + sd[1]) = vr1;
  __syncthreads();

  for (int it = 0; it < 32; ++it) {
    char* Bu = L + (it & 1) * 16384;
    char* Bn = L + ((it + 1) & 1) * 16384;
    u64x2 n0a = {0,0}, n0b = {0,0}, n1a = {0,0}, n1b = {0,0};
    if (it < 31) {
      kr0 = *(const bf16x8*)(kp + ko[0]); kr1 = *(const bf16x8*)(kp + ko[1]);
      vr0 = *(const bf16x8*)(vp + vo[0]); vr1 = *(const bf16x8*)(vp + vo[1]);
      n0a = *(const u64x2*)(mx0 + (it+1)*16);
      n0b = *(const u64x2*)(mx0 + (it+1)*16 + 2);
      n1a = *(const u64x2*)(mx1 + (it+1)*16);
      n1b = *(const u64x2*)(mx1 + (it+1)*16 + 2);
      kp += 64*DMODEL; vp += 64;
    }

    // ---- S^T = K @ Q^T (per u), C=z4 so no zero-init movs ----
    f32x4 st[2][4];
    __builtin_amdgcn_s_setprio(1);
#pragma unroll
    for (int t = 0; t < 4; ++t) {
      int row = t*16 + lq;
      bf16x8 kf0 = *(const bf16x8*)(Bu + row*128 + ((g ^ (row & 7)) << 4));
      bf16x8 kf1 = *(const bf16x8*)(Bu + row*128 + (((4 + g) ^ (row & 7)) << 4));
      st[0][t] = mfma16(kf1, qf[0][1], mfma16(kf0, qf[0][0], z4));
      st[1][t] = mfma16(kf1, qf[1][1], mfma16(kf0, qf[1][0], z4));
    }
    __builtin_amdgcn_s_setprio(0);

    // ---- fixed-scale softmax: P = exp2(s), mask via AND on packed bf16 ----
#pragma unroll
    for (int u = 0; u < 2; ++u) {
      char* pb = myP + (u*16 + lq) * 128;
#pragma unroll
      for (int t = 0; t < 4; ++t) {
        int sl = (((t*2 + (g >> 1)) ^ (lq & 7)) << 4) + ((g & 1) << 3);
        float p0 = st[u][t][0], p1 = st[u][t][1];
        float p2 = st[u][t][2], p3 = st[u][t][3];
        fexp2x4(p0, p1, p2, p3);
        u64 mt = u ? ((t < 2) ? m1a[t & 1] : m1b[t & 1])
                   : ((t < 2) ? m0a[t & 1] : m0b[t & 1]);
        union { unsigned w32[2]; u64 w64; } pw;
        pw.w32[0] = cvtpk(p0, p1);
        pw.w32[1] = cvtpk(p2, p3);
        *(u64*)(pb + sl) = pw.w64 & mt;
      }
    }
    asm volatile("s_waitcnt lgkmcnt(0)" ::: "memory");
    __builtin_amdgcn_sched_barrier(0);

    bf16x8 pf[2][2];
#pragma unroll
    for (int u = 0; u < 2; ++u) {
      char* pb = myP + (u*16 + lq) * 128;
      pf[u][0] = *(const bf16x8*)(pb + (((0 + g) ^ (lq & 7)) << 4));
      pf[u][1] = *(const bf16x8*)(pb + (((4 + g) ^ (lq & 7)) << 4));
    }

    // ---- PV + row-sums via ones-MFMA (C=z4, no init movs) ----
    __builtin_amdgcn_s_setprio(1);
    f32x4 ts0 = mfma16(pf[0][1], ones, mfma16(pf[0][0], ones, z4));
    f32x4 ts1 = mfma16(pf[1][1], ones, mfma16(pf[1][0], ones, z4));
#pragma unroll
    for (int t = 0; t < 4; ++t) {
      int row = t*16 + lq;
#pragma unroll
      for (int hh = 0; hh < 2; ++hh) {
        bf16x8 vf = *(const bf16x8*)(Bu + 8192 + row*128 + (((hh*4 + g) ^ (row & 7)) << 4));
        Oc[0][t] = mfma16(pf[0][hh], vf, Oc[0][t]);
        Oc[1][t] = mfma16(pf[1][hh], vf, Oc[1][t]);
      }
    }
    __builtin_amdgcn_s_setprio(0);
    lrow[0] += ts0;
    lrow[1] += ts1;

    if (it < 31) {
      *(bf16x8*)(Bn + sd[0]) = kr0;  *(bf16x8*)(Bn + sd[1]) = kr1;
      *(bf16x8*)(Bn + 8192 + sd[0]) = vr0;  *(bf16x8*)(Bn + 8192 + sd[1]) = vr1;
    }
    __syncthreads();
    m0a = n0a; m0b = n0b; m1a = n1a; m1b = n1b;
  }

  // ---- epilogue: write z (f32) + split hi/lo (bf16) once per element ----
#pragma unroll
  for (int u = 0; u < 2; ++u) {
    float i0 = 1.f / lrow[u][0], i1 = 1.f / lrow[u][1],
          i2 = 1.f / lrow[u][2], i3 = 1.f / lrow[u][3];
#pragma unroll
    for (int t = 0; t < 4; ++t) {
      size_t base = ((size_t)(b*S_LEN + qw + u*16 + g*4) * NHEAD + h) * DHEAD + t*16 + lq;
      float zv[4] = { Oc[u][t][0]*i0, Oc[u][t][1]*i1, Oc[u][t][2]*i2, Oc[u][t][3]*i3 };
#pragma unroll
      for (int r = 0; r < 4; ++r) {
        size_t off = base + (size_t)r * 1024;
        Zf[off] = zv[r];
        u16 hb = f2b(zv[r]);
        Zh[off] = hb;
        Zl[off] = f2b(zv[r] - b2f(hb));
      }
    }
  }
}

// ---------------- launch ----------------

extern "C" void kernel_launch(void* const* d_in, const int* in_sizes, int n_in,
                              void* d_out, int out_size, void* d_ws, size_t ws_size,
                              hipStream_t stream) {
  const float* x_q  = (const float*)d_in[0];
  const float* x_kv = (const float*)d_in[1];
  const int*   mask = (const int*)d_in[2];
  const float* W_Q  = (const float*)d_in[3];
  const float* W_K  = (const float*)d_in[4];
  const float* W_V  = (const float*)d_in[5];
  const float* W_O  = (const float*)d_in[6];
  const float* b_Q  = (const float*)d_in[7];
  const float* b_K  = (const float*)d_in[8];
  const float* b_V  = (const float*)d_in[9];
  const float* b_O  = (const float*)d_in[10];

  if (ws_size < 102760448) return;  // need 98 MB scratch

  u16* ws  = (u16*)d_ws;
  u16* XQ  = ws;                 // 8388608 elems; aliased by VT after Q-GEMM
  u16* XKV = XQ  + 8388608;      // aliased by Zh after K/V GEMMs
  u16* WQT = XKV + 8388608;      // 1048576 each
  u16* WKT = WQT + 1048576;
  u16* WVT = WKT + 1048576;
  u16* WOH = WVT + 1048576;
  u16* WOL = WOH + 1048576;
  u16* Qb  = WOL + 1048576;      // 8388608 each
  u16* Kb  = Qb  + 8388608;
  u16* Vb  = Kb  + 8388608;      // aliased by Zl after transpose_v
  u64* Mxp = (u64*)(Vb + 8388608);   // 1048576 u64 = 8MB
  u16* VTp = XQ;                 // alias: XQ dead after Q-GEMM
  u16* Zh  = XKV;                // alias: XKV dead after K/V GEMMs
  u16* Zl  = Vb;                 // alias: Vb dead after transpose_v

  float* out = (float*)d_out;
  float* zf  = out + 8388608;

  prepass<<<4096, 256, 0, stream>>>(x_q, x_kv, mask, XQ, XKV, Mxp);
  repack_w3<<<dim3(16,16,3), 256, 0, stream>>>(W_Q, W_K, W_V, WQT, WKT, WVT);
  split_wo<<<dim3(16,16), 256, 0, stream>>>(W_O, WOH, WOL);
  gemm_qkv<<<dim3(8,64,3), 256, 0, stream>>>(XQ, XKV, WQT, WKT, WVT,
                                             b_Q, b_K, b_V, Qb, Kb, Vb);
  transpose_v<<<dim3(32,64), 256, 0, stream>>>(Vb, VTp);
  attn<<<1024, 256, 0, stream>>>(Qb, Kb, VTp, Mxp, zf, Zh, Zl);
  gemm_out<<<dim3(8,64), 256, 0, stream>>>(Zh, Zl, WOH, WOL, b_O, out);
}

// Round 12
// 250.177 us; speedup vs baseline: 2.1942x; 1.0294x over previous
//
#include <hip/hip_runtime.h>

#define S_LEN 2048
#define NHEAD 16
#define DHEAD 64
#define DMODEL 1024
#define BATCH 4
#define SC2 0.18033688011112042f   // 0.125 * log2(e)

typedef short bf16x8 __attribute__((ext_vector_type(8)));
typedef float f32x4 __attribute__((ext_vector_type(4)));
typedef unsigned short u16;
typedef unsigned short u16x8 __attribute__((ext_vector_type(8)));
typedef unsigned short u16x4 __attribute__((ext_vector_type(4)));
typedef unsigned long long u64;
typedef unsigned long long u64x2 __attribute__((ext_vector_type(2)));

__device__ __forceinline__ u16 f2b(float f) {
  unsigned u = __builtin_bit_cast(unsigned, f);
  u += 0x7FFFu + ((u >> 16) & 1u);   // RTNE
  return (u16)(u >> 16);
}
__device__ __forceinline__ float b2f(u16 v) {
  unsigned u = ((unsigned)v) << 16;
  return __builtin_bit_cast(float, u);
}
__device__ __forceinline__ f32x4 mfma16(bf16x8 a, bf16x8 b, f32x4 c) {
  return __builtin_amdgcn_mfma_f32_16x16x32_bf16(a, b, c, 0, 0, 0);
}
__device__ __forceinline__ void load_lds16(const void* g, void* l) {
  __builtin_amdgcn_global_load_lds(
      (const __attribute__((address_space(1))) unsigned int*)g,
      (__attribute__((address_space(3))) unsigned int*)l, 16, 0, 0);
}
// Batched raw v_exp_f32 (= 2^x exactly); trailing s_nop covers TRANS hazard.
__device__ __forceinline__ void fexp2x4(float& a, float& b, float& c, float& d) {
  asm("v_exp_f32 %0, %0\n\t"
      "v_exp_f32 %1, %1\n\t"
      "v_exp_f32 %2, %2\n\t"
      "v_exp_f32 %3, %3\n\t"
      "s_nop 1"
      : "+v"(a), "+v"(b), "+v"(c), "+v"(d));
}
__device__ __forceinline__ unsigned cvtpk(float lo, float hi) {
  unsigned r;
  asm("v_cvt_pk_bf16_f32 %0, %1, %2" : "=v"(r) : "v"(lo), "v"(hi));
  return r;
}

// ---------------- merged prepass: cvt x_q, cvt x_kv, mask_expand ----------------

__global__ void prepass(const float* __restrict__ xq, const float* __restrict__ xkv,
                        const int* __restrict__ M,
                        u16* __restrict__ XQ, u16* __restrict__ XKV,
                        u64* __restrict__ Mex)
{
  int i = blockIdx.x * 256 + threadIdx.x;
  int stride = gridDim.x * 256;
  for (; i < 5242880; i += stride) {
    if (i < 2097152) {
      float4 v = ((const float4*)xq)[i];
      u16x4 o = { f2b(v.x), f2b(v.y), f2b(v.z), f2b(v.w) };
      ((u16x4*)XQ)[i] = o;
    } else if (i < 4194304) {
      int j = i - 2097152;
      float4 v = ((const float4*)xkv)[j];
      u16x4 o = { f2b(v.x), f2b(v.y), f2b(v.z), f2b(v.w) };
      ((u16x4*)XKV)[j] = o;
    } else {
      int idx = i - 4194304;                 // 1M groups of 4 mask elements
      int q = idx >> 9, k = (idx & 511) * 4;
      int4 v = *(const int4*)(M + (size_t)q * S_LEN + k);
      int T = k >> 6, t = (k >> 4) & 3, g = (k >> 2) & 3;
      u64 m = 0;
      if (!v.x) m |= 0xFFFFull;
      if (!v.y) m |= 0xFFFF0000ull;
      if (!v.z) m |= 0xFFFF00000000ull;
      if (!v.w) m |= 0xFFFF000000000000ull;
      Mex[((size_t)q * 32 + T) * 16 + g * 4 + t] = m;
    }
  }
}

// z=0..2: W [16][1024][64] f32 -> WT [1024 c][1024 d] bf16 (c = n*64+h), scaled
// z=3:    W_O [1024 c][1024 d] f32 -> hi/lo [1024 d][1024 c] bf16
__global__ void repack4(const float* __restrict__ WQ, const float* __restrict__ WK,
                        const float* __restrict__ WV, const float* __restrict__ WO,
                        u16* __restrict__ WQT, u16* __restrict__ WKT,
                        u16* __restrict__ WVT, u16* __restrict__ WOH,
                        u16* __restrict__ WOL)
{
  const int which = blockIdx.z;
  const int tid = threadIdx.x;
  if (which < 3) {
    __shared__ u16 t[64][66];
    const float* W = which == 0 ? WQ : (which == 1 ? WK : WV);
    u16* WT = which == 0 ? WQT : (which == 1 ? WKT : WVT);
    const float scale = which == 0 ? SC2 : 1.0f;
    const int n = blockIdx.y, d0 = blockIdx.x * 64;
    const float* src = W + (size_t)n * 65536;
    for (int p = 0; p < 4; ++p) {
      int idx = p * 256 + tid;
      int r = idx >> 4, cs = idx & 15;
      float4 v = *(const float4*)(src + (size_t)(d0 + r) * 64 + cs * 4);
      t[r][cs*4+0] = f2b(v.x*scale); t[r][cs*4+1] = f2b(v.y*scale);
      t[r][cs*4+2] = f2b(v.z*scale); t[r][cs*4+3] = f2b(v.w*scale);
    }
    __syncthreads();
    for (int p = 0; p < 2; ++p) {
      int idx = p * 256 + tid;
      int hl = idx >> 3, ds = idx & 7;
      u16x8 o;
      for (int e = 0; e < 8; ++e) o[e] = t[ds*8+e][hl];
      *(u16x8*)(WT + (size_t)(n*64 + hl) * 1024 + d0 + ds*8) = o;
    }
  } else {
    __shared__ u16 th[64][66];
    __shared__ u16 tl[64][66];
    const int d0 = blockIdx.x * 64, c0 = blockIdx.y * 64;
    for (int p = 0; p < 4; ++p) {
      int idx = p * 256 + tid;
      int r = idx >> 4, cs = idx & 15;
      float4 v = *(const float4*)(WO + (size_t)(c0 + r) * 1024 + d0 + cs * 4);
      float f[4] = {v.x, v.y, v.z, v.w};
      for (int e = 0; e < 4; ++e) {
        u16 hb = f2b(f[e]);
        th[r][cs*4+e] = hb;
        tl[r][cs*4+e] = f2b(f[e] - b2f(hb));
      }
    }
    __syncthreads();
    for (int p = 0; p < 2; ++p) {
      int idx = p * 256 + tid;
      int dr = idx >> 3, cs = idx & 7;
      u16x8 oh, ol;
      for (int e = 0; e < 8; ++e) { oh[e] = th[cs*8+e][dr]; ol[e] = tl[cs*8+e][dr]; }
      *(u16x8*)(WOH + (size_t)(d0 + dr) * 1024 + c0 + cs*8) = oh;
      *(u16x8*)(WOL + (size_t)(d0 + dr) * 1024 + c0 + cs*8) = ol;
    }
  }
}

// ---------------- merged QKV GEMM: z selects path; V writes VT directly ----------------

__global__ __launch_bounds__(256, 2)
void gemm_qkv(const u16* __restrict__ XQ, const u16* __restrict__ XKV,
              const u16* __restrict__ WQT, const u16* __restrict__ WKT,
              const u16* __restrict__ WVT,
              const float* __restrict__ bQ, const float* __restrict__ bK,
              const float* __restrict__ bV,
              u16* __restrict__ Qb, u16* __restrict__ Kb, u16* __restrict__ VT)
{
  const int which = blockIdx.z;
  const u16* A  = which == 0 ? XQ : XKV;
  const u16* Bt = which == 0 ? WQT : (which == 1 ? WKT : WVT);
  const float* bias = which == 0 ? bQ : (which == 1 ? bK : bV);
  const float bscale = which == 0 ? SC2 : 1.0f;

  __shared__ __align__(16) char As[16384];
  __shared__ __align__(16) char Bs[16384];
  const int tid = threadIdx.x, wid = tid >> 6, lane = tid & 63;
  const int lq = lane & 15, g = lane >> 4;
  const size_t am0 = (size_t)blockIdx.y * 128;
  const size_t bn0 = (size_t)blockIdx.x * 128;
  const int wr = (wid >> 1) * 64, wc = (wid & 1) * 64;
  f32x4 z4 = {0.f, 0.f, 0.f, 0.f};
  f32x4 acc[4][4];
  for (int i = 0; i < 4; ++i) for (int j = 0; j < 4; ++j) acc[i][j] = z4;
  for (int k0 = 0; k0 < DMODEL; k0 += 64) {
#pragma unroll
    for (int c = 0; c < 4; ++c) {
      int idx = c*256 + tid, r = idx >> 3, s = idx & 7;
      load_lds16(A + (am0 + r)*DMODEL + k0 + ((s ^ (r & 7)) << 3), As + idx*16);
    }
#pragma unroll
    for (int c = 0; c < 4; ++c) {
      int idx = c*256 + tid, r = idx >> 3, s = idx & 7;
      load_lds16(Bt + (bn0 + r)*DMODEL + k0 + ((s ^ (r & 7)) << 3), Bs + idx*16);
    }
    __syncthreads();
#pragma unroll
    for (int ks = 0; ks < 2; ++ks) {
      bf16x8 af[4], bfr[4];
#pragma unroll
      for (int i = 0; i < 4; ++i) {
        int row = wr + i*16 + lq;
        af[i] = *(const bf16x8*)(As + row*128 + (((ks*4 + g) ^ (row & 7)) << 4));
      }
#pragma unroll
      for (int j = 0; j < 4; ++j) {
        int row = wc + j*16 + lq;
        bfr[j] = *(const bf16x8*)(Bs + row*128 + (((ks*4 + g) ^ (row & 7)) << 4));
      }
#pragma unroll
      for (int i = 0; i < 4; ++i)
#pragma unroll
        for (int j = 0; j < 4; ++j)
          acc[i][j] = mfma16(af[i], bfr[j], acc[i][j]);
    }
    __syncthreads();
  }
  if (which < 2) {
    u16* Cout = which == 0 ? Qb : Kb;
#pragma unroll
    for (int i = 0; i < 4; ++i)
#pragma unroll
      for (int j = 0; j < 4; ++j) {
        size_t row = am0 + wr + i*16 + g*4;
        int col = (int)bn0 + wc + j*16 + lq;
        float bv = bias[col] * bscale;
#pragma unroll
        for (int r = 0; r < 4; ++r)
          Cout[(row + r)*DMODEL + col] = f2b(acc[i][j][r] + bv);
      }
  } else {
    // V: write VT[(b*16+h)*64 + dh][s] directly (fused transpose).
    // 4 acc rows = 4 consecutive s at one dh -> aligned 8B u16x4 store.
#pragma unroll
    for (int i = 0; i < 4; ++i)
#pragma unroll
      for (int j = 0; j < 4; ++j) {
        size_t row = am0 + wr + i*16 + g*4;
        int col = (int)bn0 + wc + j*16 + lq;
        float bv = bias[col];
        int bb = (int)(row >> 11), s = (int)(row & 2047);
        int hh2 = col >> 6, dh = col & 63;
        u16x4 o = { f2b(acc[i][j][0] + bv), f2b(acc[i][j][1] + bv),
                    f2b(acc[i][j][2] + bv), f2b(acc[i][j][3] + bv) };
        *(u16x4*)(VT + ((size_t)((bb*NHEAD + hh2)*DHEAD + dh))*S_LEN + s) = o;
      }
  }
}

// ---------------- out = (Zh+Zl) @ WoT^T + b_O  (all bf16 via load_lds) ----------------

__global__ __launch_bounds__(256, 2)
void gemm_out(const u16* __restrict__ Zh, const u16* __restrict__ Zl,
              const u16* __restrict__ Bh, const u16* __restrict__ Bl,
              const float* __restrict__ bias, float* __restrict__ Cout)
{
  __shared__ __align__(16) char Ah[16384];
  __shared__ __align__(16) char Al[16384];
  __shared__ __align__(16) char Bhs[16384];
  __shared__ __align__(16) char Bls[16384];
  const int tid = threadIdx.x, wid = tid >> 6, lane = tid & 63;
  const int lq = lane & 15, g = lane >> 4;
  const size_t am0 = (size_t)blockIdx.y * 128;
  const size_t bn0 = (size_t)blockIdx.x * 128;
  const int wr = (wid >> 1) * 64, wc = (wid & 1) * 64;
  f32x4 z4 = {0.f, 0.f, 0.f, 0.f};
  f32x4 acc[4][4];
  for (int i = 0; i < 4; ++i) for (int j = 0; j < 4; ++j) acc[i][j] = z4;
  for (int k0 = 0; k0 < DMODEL; k0 += 64) {
#pragma unroll
    for (int c = 0; c < 4; ++c) {
      int idx = c*256 + tid, r = idx >> 3, s = idx & 7;
      int so = (s ^ (r & 7)) << 3;
      load_lds16(Zh + (am0 + r)*DMODEL + k0 + so, Ah + idx*16);
      load_lds16(Zl + (am0 + r)*DMODEL + k0 + so, Al + idx*16);
      load_lds16(Bh + (bn0 + r)*DMODEL + k0 + so, Bhs + idx*16);
      load_lds16(Bl + (bn0 + r)*DMODEL + k0 + so, Bls + idx*16);
    }
    __syncthreads();
#pragma unroll
    for (int ks = 0; ks < 2; ++ks) {
      bf16x8 ah[4], al[4], bh4[4], bl4[4];
#pragma unroll
      for (int i = 0; i < 4; ++i) {
        int row = wr + i*16 + lq;
        int off = row*128 + (((ks*4 + g) ^ (row & 7)) << 4);
        ah[i] = *(const bf16x8*)(Ah + off);
        al[i] = *(const bf16x8*)(Al + off);
      }
#pragma unroll
      for (int j = 0; j < 4; ++j) {
        int row = wc + j*16 + lq;
        int off = row*128 + (((ks*4 + g) ^ (row & 7)) << 4);
        bh4[j] = *(const bf16x8*)(Bhs + off);
        bl4[j] = *(const bf16x8*)(Bls + off);
      }
#pragma unroll
      for (int i = 0; i < 4; ++i)
#pragma unroll
        for (int j = 0; j < 4; ++j) {
          acc[i][j] = mfma16(al[i], bh4[j], acc[i][j]);
          acc[i][j] = mfma16(ah[i], bl4[j], acc[i][j]);
          acc[i][j] = mfma16(ah[i], bh4[j], acc[i][j]);
        }
    }
    __syncthreads();
  }
#pragma unroll
  for (int i = 0; i < 4; ++i)
#pragma unroll
    for (int j = 0; j < 4; ++j) {
      size_t row = am0 + wr + i*16 + g*4;
      int col = (int)bn0 + wc + j*16 + lq;
      float bv = bias[col];
#pragma unroll
      for (int r = 0; r < 4; ++r)
        Cout[(row + r)*DMODEL + col] = acc[i][j][r] + bv;
    }
}

// ---------------- flash attention (round-8 core + Zh/Zl epilogue) ----------------
// grid 1024 blocks (XCD-swizzled (qt,h,b)), 256 threads = 4 waves x 32 q-rows
// LDS 48KB: buf{0,1} @ {0,16384}: K 8K | V 8K ; P @ 32768: per-wave 4K
__global__ __launch_bounds__(256, 3)
void attn(const u16* __restrict__ Q, const u16* __restrict__ K,
          const u16* __restrict__ VT, const u64* __restrict__ Mex,
          float* __restrict__ Zf, u16* __restrict__ Zh, u16* __restrict__ Zl)
{
  __shared__ __align__(16) char L[49152];
  const int tid = threadIdx.x, wid = tid >> 6, lane = tid & 63;
  const int lq = lane & 15, g = lane >> 4;
  const int Lb = blockIdx.x;
  const int xcd = Lb & 7, slot = Lb >> 3;
  const int qt = slot & 15, pl = slot >> 4;
  const int pair = xcd * 8 + pl;          // 0..63
  const int h = pair & 15, b = pair >> 4;
  const int q0 = qt * 128;
  const int qw = q0 + wid * 32;

  bf16x8 qf[2][2];
#pragma unroll
  for (int u = 0; u < 2; ++u) {
    const u16* qp = Q + (size_t)(b*S_LEN + qw + u*16 + lq) * DMODEL + h*DHEAD + g*8;
    qf[u][0] = *(const bf16x8*)qp;
    qf[u][1] = *(const bf16x8*)(qp + 32);
  }
  bf16x8 ones;
#pragma unroll
  for (int e = 0; e < 8; ++e) ones[e] = (short)0x3F80;

  const f32x4 z4 = {0.f, 0.f, 0.f, 0.f};
  f32x4 Oc[2][4];
#pragma unroll
  for (int u = 0; u < 2; ++u)
#pragma unroll
    for (int t = 0; t < 4; ++t) Oc[u][t] = z4;
  f32x4 lrow[2] = {z4, z4};

  const u16* kp = K + (size_t)(b*S_LEN)*DMODEL + h*DHEAD;
  const u16* vp = VT + (size_t)((b*NHEAD + h)*DHEAD)*S_LEN;
  const u64* mx0 = Mex + (size_t)(qw + lq) * 512 + g*4;
  const u64* mx1 = Mex + (size_t)(qw + 16 + lq) * 512 + g*4;
  char* myP = L + 32768 + wid*4096;

  size_t ko[2], vo[2];
  int sd[2];
#pragma unroll
  for (int c = 0; c < 2; ++c) {
    int idx = c*256 + tid, r = idx >> 3, s = idx & 7, so = (s ^ (r & 7)) << 3;
    ko[c] = (size_t)r * DMODEL + so;
    vo[c] = (size_t)r * S_LEN + so;
    sd[c] = idx * 16;
  }

  // ---- prologue: tile 0 ----
  bf16x8 kr0, kr1, vr0, vr1;
  kr0 = *(const bf16x8*)(kp + ko[0]); kr1 = *(const bf16x8*)(kp + ko[1]);
  vr0 = *(const bf16x8*)(vp + vo[0]); vr1 = *(const bf16x8*)(vp + vo[1]);
  u64x2 m0a = *(const u64x2*)(mx0), m0b = *(const u64x2*)(mx0 + 2);
  u64x2 m1a = *(const u64x2*)(mx1), m1b = *(const u64x2*)(mx1 + 2);
  kp += 64*DMODEL; vp += 64;
  *(bf16x8*)(L + sd[0]) = kr0;  *(bf16x8*)(L + sd[1]) = kr1;
  *(bf16x8*)(L + 8192 + sd[0]) = vr0;  *(bf16x8*)(L + 8192 + sd[1]) = vr1;
  __syncthreads();

  for (int it = 0; it < 32; ++it) {
    char* Bu = L + (it & 1) * 16384;
    char* Bn = L + ((it + 1) & 1) * 16384;
    u64x2 n0a = {0,0}, n0b = {0,0}, n1a = {0,0}, n1b = {0,0};
    if (it < 31) {
      kr0 = *(const bf16x8*)(kp + ko[0]); kr1 = *(const bf16x8*)(kp + ko[1]);
      vr0 = *(const bf16x8*)(vp + vo[0]); vr1 = *(const bf16x8*)(vp + vo[1]);
      n0a = *(const u64x2*)(mx0 + (it+1)*16);
      n0b = *(const u64x2*)(mx0 + (it+1)*16 + 2);
      n1a = *(const u64x2*)(mx1 + (it+1)*16);
      n1b = *(const u64x2*)(mx1 + (it+1)*16 + 2);
      kp += 64*DMODEL; vp += 64;
    }

    // ---- S^T = K @ Q^T (per u), C=z4 so no zero-init movs ----
    f32x4 st[2][4];
    __builtin_amdgcn_s_setprio(1);
#pragma unroll
    for (int t = 0; t < 4; ++t) {
      int row = t*16 + lq;
      bf16x8 kf0 = *(const bf16x8*)(Bu + row*128 + ((g ^ (row & 7)) << 4));
      bf16x8 kf1 = *(const bf16x8*)(Bu + row*128 + (((4 + g) ^ (row & 7)) << 4));
      st[0][t] = mfma16(kf1, qf[0][1], mfma16(kf0, qf[0][0], z4));
      st[1][t] = mfma16(kf1, qf[1][1], mfma16(kf0, qf[1][0], z4));
    }
    __builtin_amdgcn_s_setprio(0);

    // ---- fixed-scale softmax: P = exp2(s), mask via AND on packed bf16 ----
#pragma unroll
    for (int u = 0; u < 2; ++u) {
      char* pb = myP + (u*16 + lq) * 128;
#pragma unroll
      for (int t = 0; t < 4; ++t) {
        int sl = (((t*2 + (g >> 1)) ^ (lq & 7)) << 4) + ((g & 1) << 3);
        float p0 = st[u][t][0], p1 = st[u][t][1];
        float p2 = st[u][t][2], p3 = st[u][t][3];
        fexp2x4(p0, p1, p2, p3);
        u64 mt = u ? ((t < 2) ? m1a[t & 1] : m1b[t & 1])
                   : ((t < 2) ? m0a[t & 1] : m0b[t & 1]);
        union { unsigned w32[2]; u64 w64; } pw;
        pw.w32[0] = cvtpk(p0, p1);
        pw.w32[1] = cvtpk(p2, p3);
        *(u64*)(pb + sl) = pw.w64 & mt;
      }
    }
    asm volatile("s_waitcnt lgkmcnt(0)" ::: "memory");
    __builtin_amdgcn_sched_barrier(0);

    bf16x8 pf[2][2];
#pragma unroll
    for (int u = 0; u < 2; ++u) {
      char* pb = myP + (u*16 + lq) * 128;
      pf[u][0] = *(const bf16x8*)(pb + (((0 + g) ^ (lq & 7)) << 4));
      pf[u][1] = *(const bf16x8*)(pb + (((4 + g) ^ (lq & 7)) << 4));
    }

    // ---- PV + row-sums via ones-MFMA (C=z4, no init movs) ----
    __builtin_amdgcn_s_setprio(1);
    f32x4 ts0 = mfma16(pf[0][1], ones, mfma16(pf[0][0], ones, z4));
    f32x4 ts1 = mfma16(pf[1][1], ones, mfma16(pf[1][0], ones, z4));
#pragma unroll
    for (int t = 0; t < 4; ++t) {
      int row = t*16 + lq;
#pragma unroll
      for (int hh = 0; hh < 2; ++hh) {
        bf16x8 vf = *(const bf16x8*)(Bu + 8192 + row*128 + (((hh*4 + g) ^ (row & 7)) << 4));
        Oc[0][t] = mfma16(pf[0][hh], vf, Oc[0][t]);
        Oc[1][t] = mfma16(pf[1][hh], vf, Oc[1][t]);
      }
    }
    __builtin_amdgcn_s_setprio(0);
    lrow[0] += ts0;
    lrow[1] += ts1;

    if (it < 31) {
      *(bf16x8*)(Bn + sd[0]) = kr0;  *(bf16x8*)(Bn + sd[1]) = kr1;
      *(bf16x8*)(Bn + 8192 + sd[0]) = vr0;  *(bf16x8*)(Bn + 8192 + sd[1]) = vr1;
    }
    __syncthreads();
    m0a = n0a; m0b = n0b; m1a = n1a; m1b = n1b;
  }

  // ---- epilogue: write z (f32) + split hi/lo (bf16) once per element ----
#pragma unroll
  for (int u = 0; u < 2; ++u) {
    float i0 = 1.f / lrow[u][0], i1 = 1.f / lrow[u][1],
          i2 = 1.f / lrow[u][2], i3 = 1.f / lrow[u][3];
#pragma unroll
    for (int t = 0; t < 4; ++t) {
      size_t base = ((size_t)(b*S_LEN + qw + u*16 + g*4) * NHEAD + h) * DHEAD + t*16 + lq;
      float zv[4] = { Oc[u][t][0]*i0, Oc[u][t][1]*i1, Oc[u][t][2]*i2, Oc[u][t][3]*i3 };
#pragma unroll
      for (int r = 0; r < 4; ++r) {
        size_t off = base + (size_t)r * 1024;
        Zf[off] = zv[r];
        u16 hb = f2b(zv[r]);
        Zh[off] = hb;
        Zl[off] = f2b(zv[r] - b2f(hb));
      }
    }
  }
}

// ---------------- launch ----------------

extern "C" void kernel_launch(void* const* d_in, const int* in_sizes, int n_in,
                              void* d_out, int out_size, void* d_ws, size_t ws_size,
                              hipStream_t stream) {
  const float* x_q  = (const float*)d_in[0];
  const float* x_kv = (const float*)d_in[1];
  const int*   mask = (const int*)d_in[2];
  const float* W_Q  = (const float*)d_in[3];
  const float* W_K  = (const float*)d_in[4];
  const float* W_V  = (const float*)d_in[5];
  const float* W_O  = (const float*)d_in[6];
  const float* b_Q  = (const float*)d_in[7];
  const float* b_K  = (const float*)d_in[8];
  const float* b_V  = (const float*)d_in[9];
  const float* b_O  = (const float*)d_in[10];

  if (ws_size < 102760448) return;  // need 98 MB scratch

  u16* ws  = (u16*)d_ws;
  u16* XQ  = ws;                 // 16MB; dead after Q-GEMM -> Zl
  u16* XKV = XQ  + 8388608;      // 16MB; dead after K/V GEMMs -> Zh
  u16* WQT = XKV + 8388608;      // 2MB each
  u16* WKT = WQT + 1048576;
  u16* WVT = WKT + 1048576;
  u16* WOH = WVT + 1048576;
  u16* WOL = WOH + 1048576;
  u16* Qb  = WOL + 1048576;      // 16MB each
  u16* Kb  = Qb  + 8388608;
  u16* VTb = Kb  + 8388608;      // V GEMM writes VT layout directly here
  u64* Mxp = (u64*)(VTb + 8388608);  // 8MB
  u16* Zh  = XKV;
  u16* Zl  = XQ;

  float* out = (float*)d_out;
  float* zf  = out + 8388608;

  prepass<<<4096, 256, 0, stream>>>(x_q, x_kv, mask, XQ, XKV, Mxp);
  repack4<<<dim3(16,16,4), 256, 0, stream>>>(W_Q, W_K, W_V, W_O,
                                             WQT, WKT, WVT, WOH, WOL);
  gemm_qkv<<<dim3(8,64,3), 256, 0, stream>>>(XQ, XKV, WQT, WKT, WVT,
                                             b_Q, b_K, b_V, Qb, Kb, VTb);
  attn<<<1024, 256, 0, stream>>>(Qb, Kb, VTb, Mxp, zf, Zh, Zl);
  gemm_out<<<dim3(8,64), 256, 0, stream>>>(Zh, Zl, WOH, WOL, b_O, out);
}